// Round 1
// baseline (8731.689 us; speedup 1.0000x reference)
//
#include <hip/hip_runtime.h>
#include <math.h>

#define B_   16
#define T_   1024
#define FIN_ 1024
#define SSL_ 512
#define D_   256
#define H_   4
#define HD_  64
#define L_   4
#define P_   128
#define FF_  2048
#define M_   (B_ * T_)
#define LN_EPS 1e-5f

// ---------------------------------------------------------------------------
// GEMM (NT): C[m,n] = relu?( sum_k A[m,k] * W[n,k] + bias[n] )
// A: Md x Kd row-major, W: Nd x Kd row-major, C: Md x Nd row-major.
// BM=128, BN=64, BK=16, 256 threads, 8x4 per-thread micro-tile.
// LDS is k-major so compute reads are float4 (b128).
// Requires: Md % 128 == 0, Nd % 64 == 0, Kd % 16 == 0.
// ---------------------------------------------------------------------------
template <int RELU>
__global__ __launch_bounds__(256) void gemm_nt(
    const float* __restrict__ A, const float* __restrict__ W,
    const float* __restrict__ bias, float* __restrict__ C,
    int Md, int Nd, int Kd)
{
    __shared__ float As[16][132];  // [k][m], row stride 132 (528B, 16B-aligned)
    __shared__ float Bs[16][68];   // [k][n]

    const int tid = threadIdx.x;
    const int m0 = blockIdx.y * 128;
    const int n0 = blockIdx.x * 64;
    const int tm = (tid >> 4) * 8;   // 0..120
    const int tn = (tid & 15) * 4;   // 0..60

    float acc[8][4];
#pragma unroll
    for (int i = 0; i < 8; ++i)
#pragma unroll
        for (int j = 0; j < 4; ++j) acc[i][j] = 0.0f;

    const int lr = tid >> 2;         // 0..63
    const int lk = (tid & 3) * 4;    // 0,4,8,12

    for (int k0 = 0; k0 < Kd; k0 += 16) {
        float4 a0 = *(const float4*)(A + (size_t)(m0 + lr) * Kd + k0 + lk);
        float4 a1 = *(const float4*)(A + (size_t)(m0 + 64 + lr) * Kd + k0 + lk);
        float4 b0 = *(const float4*)(W + (size_t)(n0 + lr) * Kd + k0 + lk);
        __syncthreads();
        As[lk + 0][lr] = a0.x; As[lk + 1][lr] = a0.y;
        As[lk + 2][lr] = a0.z; As[lk + 3][lr] = a0.w;
        As[lk + 0][64 + lr] = a1.x; As[lk + 1][64 + lr] = a1.y;
        As[lk + 2][64 + lr] = a1.z; As[lk + 3][64 + lr] = a1.w;
        Bs[lk + 0][lr] = b0.x; Bs[lk + 1][lr] = b0.y;
        Bs[lk + 2][lr] = b0.z; Bs[lk + 3][lr] = b0.w;
        __syncthreads();
#pragma unroll
        for (int kk = 0; kk < 16; ++kk) {
            float4 av0 = *(const float4*)&As[kk][tm];
            float4 av1 = *(const float4*)&As[kk][tm + 4];
            float4 bv = *(const float4*)&Bs[kk][tn];
            float a[8] = {av0.x, av0.y, av0.z, av0.w, av1.x, av1.y, av1.z, av1.w};
            float bb[4] = {bv.x, bv.y, bv.z, bv.w};
#pragma unroll
            for (int i = 0; i < 8; ++i)
#pragma unroll
                for (int j = 0; j < 4; ++j) acc[i][j] += a[i] * bb[j];
        }
    }

#pragma unroll
    for (int j = 0; j < 4; ++j) {
        float bj = bias[n0 + tn + j];
#pragma unroll
        for (int i = 0; i < 8; ++i) {
            float v = acc[i][j] + bj;
            if (RELU) v = fmaxf(v, 0.0f);
            C[(size_t)(m0 + tm + i) * Nd + n0 + tn + j] = v;
        }
    }
}

// ---------------------------------------------------------------------------
// LayerNorm over last dim W (256 or 512); optional residual add first.
// One wave (64 lanes) per row; 4 waves per block.
// ---------------------------------------------------------------------------
template <int W, int RES>
__global__ __launch_bounds__(256) void ln_kernel(
    const float* __restrict__ xin, const float* __restrict__ resid,
    const float* __restrict__ w, const float* __restrict__ b,
    float* __restrict__ out)
{
    const int lane = threadIdx.x & 63;
    const int wv = threadIdx.x >> 6;
    const int row = blockIdx.x * 4 + wv;
    constexpr int NV = W / 256;  // float4's per lane

    const float* xr = xin + (size_t)row * W;
    float4 v[NV];
    float s = 0.0f, sq = 0.0f;
#pragma unroll
    for (int u = 0; u < NV; ++u) {
        int c = lane * 4 + u * 256;
        float4 t = *(const float4*)(xr + c);
        if (RES) {
            float4 r4 = *(const float4*)(resid + (size_t)row * W + c);
            t.x += r4.x; t.y += r4.y; t.z += r4.z; t.w += r4.w;
        }
        v[u] = t;
        s += t.x + t.y + t.z + t.w;
        sq += t.x * t.x + t.y * t.y + t.z * t.z + t.w * t.w;
    }
#pragma unroll
    for (int d = 1; d < 64; d <<= 1) {
        s += __shfl_xor(s, d);
        sq += __shfl_xor(sq, d);
    }
    float mean = s / (float)W;
    float var = fmaxf(sq / (float)W - mean * mean, 0.0f);
    float inv = 1.0f / sqrtf(var + LN_EPS);
#pragma unroll
    for (int u = 0; u < NV; ++u) {
        int c = lane * 4 + u * 256;
        float4 t = v[u];
        float4 wc = *(const float4*)(w + c);
        float4 bc = *(const float4*)(b + c);
        float4 o;
        o.x = (t.x - mean) * inv * wc.x + bc.x;
        o.y = (t.y - mean) * inv * wc.y + bc.y;
        o.z = (t.z - mean) * inv * wc.z + bc.z;
        o.w = (t.w - mean) * inv * wc.w + bc.w;
        *(float4*)(out + (size_t)row * W + c) = o;
    }
}

// ---------------------------------------------------------------------------
// Conv1d k=3 pad=1 over time + bias + ReLU.
// x1: (B,T,512) -> X: (B,T,256).  conv_W: (256, 512, 3).
// Block: 64 t x 64 d tile; grid (dt=4, tt=16, b=16); 256 threads, 4x4/thread.
// ---------------------------------------------------------------------------
__global__ __launch_bounds__(256) void conv_kernel(
    const float* __restrict__ x1, const float* __restrict__ cw,
    const float* __restrict__ cb, float* __restrict__ X)
{
    __shared__ float xs[66][17];   // t-1 .. t+64, 16 channels
    __shared__ float ws[64][49];   // d x (c*3+kk)

    const int dt = blockIdx.x, tt = blockIdx.y, b = blockIdx.z;
    const int tid = threadIdx.x;
    const int t0 = tt * 64;
    const int tm = (tid >> 4) * 4;  // 0..60 (time)
    const int tn = (tid & 15) * 4;  // 0..60 (channel)

    float acc[4][4];
#pragma unroll
    for (int i = 0; i < 4; ++i)
#pragma unroll
        for (int j = 0; j < 4; ++j) acc[i][j] = 0.0f;

    for (int c0 = 0; c0 < 512; c0 += 16) {
        __syncthreads();
        // load x tile: rows t0-1 .. t0+64  (66 rows x 16 c)
        for (int idx = tid; idx < 66 * 16; idx += 256) {
            int r = idx >> 4, c = idx & 15;
            int tg = t0 - 1 + r;
            float v = 0.0f;
            if (tg >= 0 && tg < T_)
                v = x1[((size_t)b * T_ + tg) * 512 + c0 + c];
            xs[r][c] = v;
        }
        // load w tile: 64 d x 16 c x 3 kk
        for (int idx = tid; idx < 64 * 48; idx += 256) {
            int d = idx / 48, rem = idx % 48;
            int c = rem / 3, kk = rem % 3;
            ws[d][rem] = cw[(size_t)(dt * 64 + d) * 1536 + (c0 + c) * 3 + kk];
        }
        __syncthreads();
#pragma unroll
        for (int c = 0; c < 16; ++c) {
#pragma unroll
            for (int kk = 0; kk < 3; ++kk) {
                float a0 = xs[tm + 0 + kk][c];
                float a1 = xs[tm + 1 + kk][c];
                float a2 = xs[tm + 2 + kk][c];
                float a3 = xs[tm + 3 + kk][c];
                float w0 = ws[tn + 0][c * 3 + kk];
                float w1 = ws[tn + 1][c * 3 + kk];
                float w2 = ws[tn + 2][c * 3 + kk];
                float w3 = ws[tn + 3][c * 3 + kk];
                acc[0][0] += a0 * w0; acc[0][1] += a0 * w1; acc[0][2] += a0 * w2; acc[0][3] += a0 * w3;
                acc[1][0] += a1 * w0; acc[1][1] += a1 * w1; acc[1][2] += a1 * w2; acc[1][3] += a1 * w3;
                acc[2][0] += a2 * w0; acc[2][1] += a2 * w1; acc[2][2] += a2 * w2; acc[2][3] += a2 * w3;
                acc[3][0] += a3 * w0; acc[3][1] += a3 * w1; acc[3][2] += a3 * w2; acc[3][3] += a3 * w3;
            }
        }
    }
#pragma unroll
    for (int i = 0; i < 4; ++i) {
#pragma unroll
        for (int j = 0; j < 4; ++j) {
            int d = dt * 64 + tn + j;
            float v = acc[i][j] + cb[d];
            v = fmaxf(v, 0.0f);
            X[((size_t)b * T_ + t0 + tm + i) * 256 + d] = v;
        }
    }
}

// ---------------------------------------------------------------------------
// Flash attention (fp32).  qkv: (B,T,768) [q|k|v, each head h at h*64].
// Block = one (b, h, 64-row q-tile); 256 threads.
// Thread (row=tid>>2, cg=tid&3): owns s/p cols cg*16..+15, o cols cg*16..+15.
// ---------------------------------------------------------------------------
__global__ __launch_bounds__(256) void attn_kernel(
    const float* __restrict__ qkv, const int* __restrict__ lens,
    float* __restrict__ O)
{
    __shared__ float qs[64][68];
    __shared__ float ks[64][68];
    __shared__ float vs[64][68];

    const int qt = blockIdx.x, h = blockIdx.y, b = blockIdx.z;
    const int tid = threadIdx.x;
    const int len = lens[b];
    const int row = tid >> 2;
    const int cg = tid & 3;
    const int laneBase = (tid & 63) & ~3;
    const size_t base = (size_t)b * T_ * 768;

    for (int idx = tid; idx < 64 * 16; idx += 256) {
        int r = idx >> 4, c4 = (idx & 15) * 4;
        *(float4*)&qs[r][c4] =
            *(const float4*)(qkv + base + (size_t)(qt * 64 + r) * 768 + h * 64 + c4);
    }

    float m = -3e38f, l = 0.0f;
    float o[16];
#pragma unroll
    for (int j = 0; j < 16; ++j) o[j] = 0.0f;

    for (int kt = 0; kt < 16; ++kt) {
        __syncthreads();
        for (int idx = tid; idx < 64 * 16; idx += 256) {
            int r = idx >> 4, c4 = (idx & 15) * 4;
            const float* src = qkv + base + (size_t)(kt * 64 + r) * 768 + h * 64 + c4;
            *(float4*)&ks[r][c4] = *(const float4*)(src + 256);
            *(float4*)&vs[r][c4] = *(const float4*)(src + 512);
        }
        __syncthreads();

        float s[16];
#pragma unroll
        for (int i = 0; i < 16; ++i) s[i] = 0.0f;
#pragma unroll
        for (int d4 = 0; d4 < 16; ++d4) {
            float4 q4 = *(const float4*)&qs[row][d4 * 4];
#pragma unroll
            for (int i = 0; i < 16; ++i) {
                float4 k4 = *(const float4*)&ks[cg * 16 + i][d4 * 4];
                s[i] += q4.x * k4.x + q4.y * k4.y + q4.z * k4.z + q4.w * k4.w;
            }
        }
        float mt = -3e38f;
#pragma unroll
        for (int i = 0; i < 16; ++i) {
            int kg = kt * 64 + cg * 16 + i;
            s[i] = (kg < len) ? s[i] * 0.125f : -1e30f;
            mt = fmaxf(mt, s[i]);
        }
        mt = fmaxf(mt, __shfl_xor(mt, 1));
        mt = fmaxf(mt, __shfl_xor(mt, 2));
        float mnew = fmaxf(m, mt);
        float alpha = expf(m - mnew);
        float p[16];
        float ts = 0.0f;
#pragma unroll
        for (int i = 0; i < 16; ++i) {
            p[i] = expf(s[i] - mnew);
            ts += p[i];
        }
        ts += __shfl_xor(ts, 1);
        ts += __shfl_xor(ts, 2);
        l = l * alpha + ts;
        m = mnew;
#pragma unroll
        for (int j = 0; j < 16; ++j) o[j] *= alpha;
#pragma unroll
        for (int g = 0; g < 4; ++g) {
#pragma unroll
            for (int i = 0; i < 16; ++i) {
                float pv = __shfl(p[i], laneBase + g);
#pragma unroll
                for (int j4 = 0; j4 < 4; ++j4) {
                    float4 v4 = *(const float4*)&vs[g * 16 + i][cg * 16 + j4 * 4];
                    o[j4 * 4 + 0] += pv * v4.x;
                    o[j4 * 4 + 1] += pv * v4.y;
                    o[j4 * 4 + 2] += pv * v4.z;
                    o[j4 * 4 + 3] += pv * v4.w;
                }
            }
        }
    }
    float invl = 1.0f / l;
    size_t op = ((size_t)b * T_ + qt * 64 + row) * 256 + h * 64 + cg * 16;
#pragma unroll
    for (int j4 = 0; j4 < 4; ++j4) {
        float4 t;
        t.x = o[j4 * 4 + 0] * invl;
        t.y = o[j4 * 4 + 1] * invl;
        t.z = o[j4 * 4 + 2] * invl;
        t.w = o[j4 * 4 + 3] * invl;
        *(float4*)(O + op + j4 * 4) = t;
    }
}

// ---------------------------------------------------------------------------
// Frame score: fs = h . fs2_W + fs2_b, masked by t < len[b].  One wave/row.
// ---------------------------------------------------------------------------
__global__ __launch_bounds__(256) void frame_score_kernel(
    const float* __restrict__ hbuf, const float* __restrict__ w2,
    const float* __restrict__ b2, const int* __restrict__ lens,
    float* __restrict__ frame_out)
{
    const int lane = threadIdx.x & 63;
    const int wv = threadIdx.x >> 6;
    const int rowm = blockIdx.x * 4 + wv;
    float4 hv = *(const float4*)(hbuf + (size_t)rowm * 256 + lane * 4);
    float4 w4 = *(const float4*)(w2 + lane * 4);
    float s = hv.x * w4.x + hv.y * w4.y + hv.z * w4.z + hv.w * w4.w;
#pragma unroll
    for (int d = 1; d < 64; d <<= 1) s += __shfl_xor(s, d);
    if (lane == 0) {
        int b = rowm >> 10, t = rowm & 1023;
        float fs = s + b2[0];
        frame_out[rowm] = (t < lens[b]) ? fs : 0.0f;
    }
}

// ---------------------------------------------------------------------------
// Phoneme segment means + utterance/fluency/prosody.  One block (64 thr) per b.
// ---------------------------------------------------------------------------
__global__ __launch_bounds__(64) void phoneme_kernel(
    const float* __restrict__ frame, const int* __restrict__ plen,
    float* __restrict__ pscore, float* __restrict__ utt,
    float* __restrict__ flu, float* __restrict__ pros)
{
    __shared__ float cs[T_ + 1];
    __shared__ float ps[P_];
    __shared__ int pmk[P_];

    const int b = blockIdx.x;
    const int lane = threadIdx.x;

    // wave-parallel prefix sum of frame[b, :]
    float loc[16];
    float run = 0.0f;
#pragma unroll
    for (int i = 0; i < 16; ++i) {
        run += frame[(size_t)b * T_ + lane * 16 + i];
        loc[i] = run;
    }
    float lanesum = run;
    float incl = lanesum;
#pragma unroll
    for (int d = 1; d < 64; d <<= 1) {
        float y = __shfl_up(incl, d);
        if (lane >= d) incl += y;
    }
    float excl = incl - lanesum;
#pragma unroll
    for (int i = 0; i < 16; ++i) cs[lane * 16 + i + 1] = loc[i] + excl;
    if (lane == 0) cs[0] = 0.0f;
    __syncthreads();

    if (lane == 0) {
        int cum = 0, valid = 1;
        float psum = 0.0f;
        int pcnt = 0;
        for (int p = 0; p < P_; ++p) {
            int lp = plen[b * P_ + p];
            if (lp <= 0) valid = 0;
            int eff = valid ? lp : 0;
            int start = cum; if (start > T_) start = T_; if (start < 0) start = 0;
            cum += eff;
            int end = cum; if (end > T_) end = T_; if (end < 0) end = 0;
            int cnt = end - start;
            float score = (cnt > 0) ? (cs[end] - cs[start]) / (float)cnt : 0.0f;
            ps[p] = score;
            pmk[p] = (lp > 0) ? 1 : 0;
            if (lp > 0) { psum += score; pcnt += 1; }
            pscore[b * P_ + p] = score;
        }
        int pc = pcnt > 0 ? pcnt : 1;
        float u = psum / (float)pc;
        float vsum = 0.0f;
        for (int p = 0; p < P_; ++p) {
            float d = ps[p] - u;
            if (pmk[p]) vsum += d * d;
        }
        float pstd = sqrtf(vsum / (float)pc);
        float f = 100.0f - fminf(pstd * 10.0f, 100.0f);
        f = fmaxf(f, 0.0f);
        utt[b] = u;
        flu[b] = f;
        pros[b] = 0.5f * (u + f);
    }
}

// ---------------------------------------------------------------------------
extern "C" void kernel_launch(void* const* d_in, const int* in_sizes, int n_in,
                              void* d_out, int out_size, void* d_ws, size_t ws_size,
                              hipStream_t stream)
{
    const float* features = (const float*)d_in[0];
    const int* feat_len = (const int*)d_in[1];
    const int* plen = (const int*)d_in[2];
    const float* ssl_W = (const float*)d_in[3];
    const float* ssl_b = (const float*)d_in[4];
    const float* ln0_w = (const float*)d_in[5];
    const float* ln0_b = (const float*)d_in[6];
    const float* conv_W = (const float*)d_in[7];
    const float* conv_b = (const float*)d_in[8];
    const float* qkv_W = (const float*)d_in[9];
    const float* qkv_b = (const float*)d_in[10];
    const float* out_W = (const float*)d_in[11];
    const float* out_b = (const float*)d_in[12];
    const float* ln1_w = (const float*)d_in[13];
    const float* ln1_b = (const float*)d_in[14];
    const float* ff1_W = (const float*)d_in[15];
    const float* ff1_b = (const float*)d_in[16];
    const float* ff2_W = (const float*)d_in[17];
    const float* ff2_b = (const float*)d_in[18];
    const float* ln2_w = (const float*)d_in[19];
    const float* ln2_b = (const float*)d_in[20];
    const float* fs1_W = (const float*)d_in[21];
    const float* fs1_b = (const float*)d_in[22];
    const float* fs2_W = (const float*)d_in[23];
    const float* fs2_b = (const float*)d_in[24];

    float* ws = (float*)d_ws;
    float* x512 = ws;                              // M*512
    float* X = x512 + (size_t)M_ * 512;            // M*256
    float* QKV = X + (size_t)M_ * 256;             // M*768 (also FF1 chunk buf)
    float* Obuf = QKV + (size_t)M_ * 768;          // M*256
    float* T1 = Obuf + (size_t)M_ * 256;           // M*256

    float* frame = (float*)d_out;                  // 16384
    float* pscore = frame + M_;                    // 2048
    float* uttp = pscore + B_ * P_;                // 16
    float* flup = uttp + B_;                       // 16
    float* prosp = flup + B_;                      // 16

    // 1) SSL linear + ReLU, then LN0 (in place)
    gemm_nt<1><<<dim3(SSL_ / 64, M_ / 128), 256, 0, stream>>>(
        features, ssl_W, ssl_b, x512, M_, SSL_, FIN_);
    ln_kernel<512, 0><<<M_ / 4, 256, 0, stream>>>(x512, nullptr, ln0_w, ln0_b, x512);

    // 2) Conv1d + ReLU -> X
    conv_kernel<<<dim3(4, 16, 16), 256, 0, stream>>>(x512, conv_W, conv_b, X);

    // 3) Transformer layers
    for (int l = 0; l < L_; ++l) {
        gemm_nt<0><<<dim3(768 / 64, M_ / 128), 256, 0, stream>>>(
            X, qkv_W + (size_t)l * 768 * 256, qkv_b + l * 768, QKV, M_, 768, 256);
        attn_kernel<<<dim3(16, H_, B_), 256, 0, stream>>>(QKV, feat_len, Obuf);
        gemm_nt<0><<<dim3(256 / 64, M_ / 128), 256, 0, stream>>>(
            Obuf, out_W + (size_t)l * 256 * 256, out_b + l * 256, T1, M_, 256, 256);
        ln_kernel<256, 1><<<M_ / 4, 256, 0, stream>>>(
            T1, X, ln1_w + l * 256, ln1_b + l * 256, X);
        // FFN, chunked over M (4 x 4096 rows), FF1 output reuses QKV buffer
        for (int c = 0; c < 4; ++c) {
            const float* Ac = X + (size_t)c * 4096 * 256;
            gemm_nt<1><<<dim3(FF_ / 64, 4096 / 128), 256, 0, stream>>>(
                Ac, ff1_W + (size_t)l * FF_ * 256, ff1_b + l * FF_, QKV, 4096, FF_, 256);
            gemm_nt<0><<<dim3(256 / 64, 4096 / 128), 256, 0, stream>>>(
                QKV, ff2_W + (size_t)l * 256 * FF_, ff2_b + l * 256,
                T1 + (size_t)c * 4096 * 256, 4096, 256, FF_);
        }
        ln_kernel<256, 1><<<M_ / 4, 256, 0, stream>>>(
            T1, X, ln2_w + l * 256, ln2_b + l * 256, X);
    }

    // 4) Frame scorer
    gemm_nt<1><<<dim3(256 / 64, M_ / 128), 256, 0, stream>>>(
        X, fs1_W, fs1_b, T1, M_, 256, 256);
    frame_score_kernel<<<M_ / 4, 256, 0, stream>>>(T1, fs2_W, fs2_b, feat_len, frame);

    // 5) Phoneme/utterance epilogue
    phoneme_kernel<<<B_, 64, 0, stream>>>(frame, plen, pscore, uttp, flup, prosp);
}

// Round 4
// 1826.918 us; speedup vs baseline: 4.7795x; 4.7795x over previous
//
#include <hip/hip_runtime.h>
#include <math.h>

#define B_   16
#define T_   1024
#define FIN_ 1024
#define SSL_ 512
#define D_   256
#define H_   4
#define HD_  64
#define L_   4
#define P_   128
#define FF_  2048
#define M_   (B_ * T_)
#define LN_EPS 1e-5f

typedef __attribute__((ext_vector_type(8))) short bf16x8;
typedef __attribute__((ext_vector_type(4))) float f32x4;

__device__ inline unsigned short f2bf(float f) {
    unsigned int u = __float_as_uint(f);
    u += 0x7fffu + ((u >> 16) & 1u);   // round-to-nearest-even
    return (unsigned short)(u >> 16);
}

__device__ inline bf16x8 pack8(float4 a, float4 b) {
    bf16x8 t;
    t[0] = (short)f2bf(a.x); t[1] = (short)f2bf(a.y);
    t[2] = (short)f2bf(a.z); t[3] = (short)f2bf(a.w);
    t[4] = (short)f2bf(b.x); t[5] = (short)f2bf(b.y);
    t[6] = (short)f2bf(b.z); t[7] = (short)f2bf(b.w);
    return t;
}

// ---------------------------------------------------------------------------
// bf16 MFMA GEMM (NT): C[m,n] = relu?( sum_k A[m,k]*W[n,k] + bias[n] )
// A: Md x Kd fp32 row-major, W: Nd x Kd fp32 row-major (converted to bf16 in
// staging). Tile 128x128, BK=32, 256 threads = 4 waves (2x2 of 64x64).
// LDS tiles [row][32k] bf16, 64B rows, XOR swizzle on 16B slots:
//   byte = row*64 + ((chunk<<4) ^ (((row>>1)&3)<<4))  -> 2-way max (free).
// Requires Md%128==0, Nd%128==0, Kd%32==0.
// ---------------------------------------------------------------------------
template <int RELU>
__global__ __launch_bounds__(256) void gemm_bf16(
    const float* __restrict__ A, const float* __restrict__ W,
    const float* __restrict__ bias, float* __restrict__ C,
    int Md, int Nd, int Kd)
{
    __shared__ __align__(16) unsigned short As[128 * 32];
    __shared__ __align__(16) unsigned short Bs[128 * 32];
    char* AsB = (char*)As;
    char* BsB = (char*)Bs;

    const int tid = threadIdx.x;
    const int m0 = blockIdx.y * 128, n0 = blockIdx.x * 128;
    const int w = tid >> 6, l = tid & 63;
    const int lr = l & 15, lg = l >> 4;
    const int wr = w >> 1, wc = w & 1;

    f32x4 acc[4][4];
#pragma unroll
    for (int mi = 0; mi < 4; ++mi)
#pragma unroll
        for (int ni = 0; ni < 4; ++ni) acc[mi][ni] = (f32x4){0.f, 0.f, 0.f, 0.f};

    int aoff[4], boff[4];
#pragma unroll
    for (int mi = 0; mi < 4; ++mi) {
        int row = wr * 64 + mi * 16 + lr;
        aoff[mi] = row * 64 + ((lg * 16) ^ (((row >> 1) & 3) << 4));
    }
#pragma unroll
    for (int ni = 0; ni < 4; ++ni) {
        int row = wc * 64 + ni * 16 + lr;
        boff[ni] = row * 64 + ((lg * 16) ^ (((row >> 1) & 3) << 4));
    }
    int srow[2], soff[2], schk[2];
#pragma unroll
    for (int jj = 0; jj < 2; ++jj) {
        int id = tid + jj * 256;
        int row = id >> 2, c = id & 3;
        srow[jj] = row; schk[jj] = c;
        soff[jj] = row * 64 + ((c << 4) ^ (((row >> 1) & 3) << 4));
    }

    for (int k0 = 0; k0 < Kd; k0 += 32) {
        __syncthreads();
#pragma unroll
        for (int jj = 0; jj < 2; ++jj) {
            const float* ap = A + (size_t)(m0 + srow[jj]) * Kd + k0 + schk[jj] * 8;
            float4 f0 = *(const float4*)ap;
            float4 f1 = *(const float4*)(ap + 4);
            *(bf16x8*)(AsB + soff[jj]) = pack8(f0, f1);
            const float* wp = W + (size_t)(n0 + srow[jj]) * Kd + k0 + schk[jj] * 8;
            float4 g0 = *(const float4*)wp;
            float4 g1 = *(const float4*)(wp + 4);
            *(bf16x8*)(BsB + soff[jj]) = pack8(g0, g1);
        }
        __syncthreads();
        bf16x8 a[4], bb[4];
#pragma unroll
        for (int mi = 0; mi < 4; ++mi) a[mi] = *(bf16x8*)(AsB + aoff[mi]);
#pragma unroll
        for (int ni = 0; ni < 4; ++ni) bb[ni] = *(bf16x8*)(BsB + boff[ni]);
#pragma unroll
        for (int mi = 0; mi < 4; ++mi)
#pragma unroll
            for (int ni = 0; ni < 4; ++ni)
                acc[mi][ni] = __builtin_amdgcn_mfma_f32_16x16x32_bf16(
                    a[mi], bb[ni], acc[mi][ni], 0, 0, 0);
    }

#pragma unroll
    for (int ni = 0; ni < 4; ++ni) {
        int col = n0 + wc * 64 + ni * 16 + lr;
        float bj = bias[col];
#pragma unroll
        for (int mi = 0; mi < 4; ++mi) {
#pragma unroll
            for (int r = 0; r < 4; ++r) {
                int rowg = m0 + wr * 64 + mi * 16 + lg * 4 + r;
                float v = acc[mi][ni][r] + bj;
                if (RELU) v = fmaxf(v, 0.0f);
                C[(size_t)rowg * Nd + col] = v;
            }
        }
    }
}

// ---------------------------------------------------------------------------
// bf16 MFMA flash attention.  qkv: (B,T,768) fp32 [q|k|v].
// Block = (qt 64 rows, h, b), 256 thr = 4 waves; wave w owns 16 q-rows.
// Swapped S^T = K·Q^T so softmax reduces over lane groups (2x shfl_xor).
// PV as O^T = V^T·P with V transposed in staging; P^T per-wave in LDS.
// All LDS rows 128B with byte ^= ((row&7)<<4) swizzle -> conflict-free b128.
// ---------------------------------------------------------------------------
__global__ __launch_bounds__(256) void attn_mfma(
    const float* __restrict__ qkv, const int* __restrict__ lens,
    float* __restrict__ O)
{
    __shared__ __align__(16) unsigned short Kt[64 * 64];     // [k][hd]
    __shared__ __align__(16) unsigned short Vt[64 * 64];     // [d][k]
    __shared__ __align__(16) unsigned short Pt[4][16 * 64];  // per-wave [q][k]

    const int qt = blockIdx.x, h = blockIdx.y, b = blockIdx.z;
    const int tid = threadIdx.x;
    const int w = tid >> 6, l = tid & 63;
    const int lr = l & 15, lg = l >> 4;
    const int len = lens[b];
    const size_t base = (size_t)b * (T_ * 768);
    const int q0 = qt * 64 + w * 16;

    char* KtB = (char*)Kt;
    char* VtB = (char*)Vt;
    char* PtB = (char*)(Pt[w]);

    // Q fragments (held in registers): lane: q=q0+lr, hd=lg*8+j (+32*half)
    bf16x8 qf[2];
#pragma unroll
    for (int half = 0; half < 2; ++half) {
        const float* qp = qkv + base + (size_t)(q0 + lr) * 768 + h * 64 + lg * 8 + half * 32;
        float4 f0 = *(const float4*)qp;
        float4 f1 = *(const float4*)(qp + 4);
        qf[half] = pack8(f0, f1);
    }

    float mrun = -3e38f, lrun = 0.0f;
    f32x4 acc_o[4];
#pragma unroll
    for (int td = 0; td < 4; ++td) acc_o[td] = (f32x4){0.f, 0.f, 0.f, 0.f};

    // staging task geometry (512 16B-chunk tasks, 2/thread)
    int skr[2], skc[2];
#pragma unroll
    for (int jj = 0; jj < 2; ++jj) {
        int id = tid + jj * 256;
        skr[jj] = id >> 3; skc[jj] = id & 7;
    }

    for (int tk = 0; tk < 16; ++tk) {
        const int kv0 = tk * 64;
        __syncthreads();
#pragma unroll
        for (int jj = 0; jj < 2; ++jj) {
            int kr = skr[jj], c = skc[jj];
            const float* kp = qkv + base + (size_t)(kv0 + kr) * 768 + h * 64 + 256 + c * 8;
            float4 f0 = *(const float4*)kp;
            float4 f1 = *(const float4*)(kp + 4);
            *(bf16x8*)(KtB + kr * 128 + (((c << 4)) ^ ((kr & 7) << 4))) = pack8(f0, f1);
            const float* vp = kp + 256;
            float4 g0 = *(const float4*)vp;
            float4 g1 = *(const float4*)(vp + 4);
            float vv[8] = {g0.x, g0.y, g0.z, g0.w, g1.x, g1.y, g1.z, g1.w};
#pragma unroll
            for (int j = 0; j < 8; ++j) {
                int d = c * 8 + j;
                *(unsigned short*)(VtB + d * 128 + ((kr * 2) ^ ((d & 7) << 4))) = f2bf(vv[j]);
            }
        }
        __syncthreads();

        // S^T tiles: acc_s[kt] -> lane: q=lr(col), k=kv0+kt*16+lg*4+r(row)
        f32x4 accs[4];
#pragma unroll
        for (int kt = 0; kt < 4; ++kt) {
            int row = kt * 16 + lr;
            int rb = row * 128, sw = (row & 7) << 4;
            bf16x8 k0 = *(bf16x8*)(KtB + rb + ((lg * 16) ^ sw));
            bf16x8 k1 = *(bf16x8*)(KtB + rb + ((lg * 16 + 64) ^ sw));
            f32x4 z = (f32x4){0.f, 0.f, 0.f, 0.f};
            f32x4 t = __builtin_amdgcn_mfma_f32_16x16x32_bf16(k0, qf[0], z, 0, 0, 0);
            accs[kt] = __builtin_amdgcn_mfma_f32_16x16x32_bf16(k1, qf[1], t, 0, 0, 0);
        }

        float p[16];
        float pmax = -3e38f;
#pragma unroll
        for (int kt = 0; kt < 4; ++kt)
#pragma unroll
            for (int r = 0; r < 4; ++r) {
                int kidx = kv0 + kt * 16 + lg * 4 + r;
                float v = (kidx < len) ? accs[kt][r] * 0.125f : -1e30f;
                p[kt * 4 + r] = v;
                pmax = fmaxf(pmax, v);
            }
        pmax = fmaxf(pmax, __shfl_xor(pmax, 16));
        pmax = fmaxf(pmax, __shfl_xor(pmax, 32));
        float mnew = fmaxf(mrun, pmax);
        float alpha = expf(mrun - mnew);
        float psum = 0.0f;
#pragma unroll
        for (int i = 0; i < 16; ++i) {
            float e = expf(p[i] - mnew);
            p[i] = e;
            psum += e;
        }
        psum += __shfl_xor(psum, 16);
        psum += __shfl_xor(psum, 32);
        lrun = lrun * alpha + psum;
        mrun = mnew;
#pragma unroll
        for (int td = 0; td < 4; ++td) acc_o[td] *= alpha;

        // write P^T (stored [q][k] bf16): lane q=lr, k=kt*16+lg*4+r
        const int swq = (lr & 7) << 4;
#pragma unroll
        for (int kt = 0; kt < 4; ++kt) {
            unsigned int p01 = (unsigned int)f2bf(p[kt * 4 + 0]) |
                               ((unsigned int)f2bf(p[kt * 4 + 1]) << 16);
            unsigned int p23 = (unsigned int)f2bf(p[kt * 4 + 2]) |
                               ((unsigned int)f2bf(p[kt * 4 + 3]) << 16);
            uint2 pw; pw.x = p01; pw.y = p23;
            *(uint2*)(PtB + lr * 128 + ((kt * 32 + lg * 8) ^ swq)) = pw;
        }
        // PV: B-operand = P[k][q] read from Pt rows (wave-local, lgkm-ordered)
        bf16x8 pf0 = *(bf16x8*)(PtB + lr * 128 + ((lg * 16) ^ swq));
        bf16x8 pf1 = *(bf16x8*)(PtB + lr * 128 + ((lg * 16 + 64) ^ swq));
#pragma unroll
        for (int td = 0; td < 4; ++td) {
            int d = td * 16 + lr;
            int db = d * 128, swd = (d & 7) << 4;
            bf16x8 v0 = *(bf16x8*)(VtB + db + ((lg * 16) ^ swd));
            bf16x8 v1 = *(bf16x8*)(VtB + db + ((lg * 16 + 64) ^ swd));
            acc_o[td] = __builtin_amdgcn_mfma_f32_16x16x32_bf16(v0, pf0, acc_o[td], 0, 0, 0);
            acc_o[td] = __builtin_amdgcn_mfma_f32_16x16x32_bf16(v1, pf1, acc_o[td], 0, 0, 0);
        }
    }

    float inv = 1.0f / lrun;
    const int tglob = qt * 64 + w * 16 + lr;
#pragma unroll
    for (int td = 0; td < 4; ++td)
#pragma unroll
        for (int r = 0; r < 4; ++r) {
            int d = td * 16 + lg * 4 + r;
            O[((size_t)b * T_ + tglob) * 256 + h * 64 + d] = acc_o[td][r] * inv;
        }
}

// ---------------------------------------------------------------------------
// LayerNorm over last dim W (256 or 512); optional residual add first.
// ---------------------------------------------------------------------------
template <int W, int RES>
__global__ __launch_bounds__(256) void ln_kernel(
    const float* __restrict__ xin, const float* __restrict__ resid,
    const float* __restrict__ w, const float* __restrict__ b,
    float* __restrict__ out)
{
    const int lane = threadIdx.x & 63;
    const int wv = threadIdx.x >> 6;
    const int row = blockIdx.x * 4 + wv;
    constexpr int NV = W / 256;

    const float* xr = xin + (size_t)row * W;
    float4 v[NV];
    float s = 0.0f, sq = 0.0f;
#pragma unroll
    for (int u = 0; u < NV; ++u) {
        int c = lane * 4 + u * 256;
        float4 t = *(const float4*)(xr + c);
        if (RES) {
            float4 r4 = *(const float4*)(resid + (size_t)row * W + c);
            t.x += r4.x; t.y += r4.y; t.z += r4.z; t.w += r4.w;
        }
        v[u] = t;
        s += t.x + t.y + t.z + t.w;
        sq += t.x * t.x + t.y * t.y + t.z * t.z + t.w * t.w;
    }
#pragma unroll
    for (int d = 1; d < 64; d <<= 1) {
        s += __shfl_xor(s, d);
        sq += __shfl_xor(sq, d);
    }
    float mean = s / (float)W;
    float var = fmaxf(sq / (float)W - mean * mean, 0.0f);
    float inv = 1.0f / sqrtf(var + LN_EPS);
#pragma unroll
    for (int u = 0; u < NV; ++u) {
        int c = lane * 4 + u * 256;
        float4 t = v[u];
        float4 wc = *(const float4*)(w + c);
        float4 bc = *(const float4*)(b + c);
        float4 o;
        o.x = (t.x - mean) * inv * wc.x + bc.x;
        o.y = (t.y - mean) * inv * wc.y + bc.y;
        o.z = (t.z - mean) * inv * wc.z + bc.z;
        o.w = (t.w - mean) * inv * wc.w + bc.w;
        *(float4*)(out + (size_t)row * W + c) = o;
    }
}

// ---------------------------------------------------------------------------
// Conv1d k=3 pad=1 over time + bias + ReLU (fp32).
// ---------------------------------------------------------------------------
__global__ __launch_bounds__(256) void conv_kernel(
    const float* __restrict__ x1, const float* __restrict__ cw,
    const float* __restrict__ cb, float* __restrict__ X)
{
    __shared__ float xs[66][17];
    __shared__ float ws[64][49];

    const int dt = blockIdx.x, tt = blockIdx.y, b = blockIdx.z;
    const int tid = threadIdx.x;
    const int t0 = tt * 64;
    const int tm = (tid >> 4) * 4;
    const int tn = (tid & 15) * 4;

    float acc[4][4];
#pragma unroll
    for (int i = 0; i < 4; ++i)
#pragma unroll
        for (int j = 0; j < 4; ++j) acc[i][j] = 0.0f;

    for (int c0 = 0; c0 < 512; c0 += 16) {
        __syncthreads();
        for (int idx = tid; idx < 66 * 16; idx += 256) {
            int r = idx >> 4, c = idx & 15;
            int tg = t0 - 1 + r;
            float v = 0.0f;
            if (tg >= 0 && tg < T_)
                v = x1[((size_t)b * T_ + tg) * 512 + c0 + c];
            xs[r][c] = v;
        }
        for (int idx = tid; idx < 64 * 48; idx += 256) {
            int d = idx / 48, rem = idx % 48;
            int c = rem / 3, kk = rem % 3;
            ws[d][rem] = cw[(size_t)(dt * 64 + d) * 1536 + (c0 + c) * 3 + kk];
        }
        __syncthreads();
#pragma unroll
        for (int c = 0; c < 16; ++c) {
#pragma unroll
            for (int kk = 0; kk < 3; ++kk) {
                float a0 = xs[tm + 0 + kk][c];
                float a1 = xs[tm + 1 + kk][c];
                float a2 = xs[tm + 2 + kk][c];
                float a3 = xs[tm + 3 + kk][c];
                float w0 = ws[tn + 0][c * 3 + kk];
                float w1 = ws[tn + 1][c * 3 + kk];
                float w2 = ws[tn + 2][c * 3 + kk];
                float w3 = ws[tn + 3][c * 3 + kk];
                acc[0][0] += a0 * w0; acc[0][1] += a0 * w1; acc[0][2] += a0 * w2; acc[0][3] += a0 * w3;
                acc[1][0] += a1 * w0; acc[1][1] += a1 * w1; acc[1][2] += a1 * w2; acc[1][3] += a1 * w3;
                acc[2][0] += a2 * w0; acc[2][1] += a2 * w1; acc[2][2] += a2 * w2; acc[2][3] += a2 * w3;
                acc[3][0] += a3 * w0; acc[3][1] += a3 * w1; acc[3][2] += a3 * w2; acc[3][3] += a3 * w3;
            }
        }
    }
#pragma unroll
    for (int i = 0; i < 4; ++i) {
#pragma unroll
        for (int j = 0; j < 4; ++j) {
            int d = dt * 64 + tn + j;
            float v = acc[i][j] + cb[d];
            v = fmaxf(v, 0.0f);
            X[((size_t)b * T_ + t0 + tm + i) * 256 + d] = v;
        }
    }
}

// ---------------------------------------------------------------------------
__global__ __launch_bounds__(256) void frame_score_kernel(
    const float* __restrict__ hbuf, const float* __restrict__ w2,
    const float* __restrict__ b2, const int* __restrict__ lens,
    float* __restrict__ frame_out)
{
    const int lane = threadIdx.x & 63;
    const int wv = threadIdx.x >> 6;
    const int rowm = blockIdx.x * 4 + wv;
    float4 hv = *(const float4*)(hbuf + (size_t)rowm * 256 + lane * 4);
    float4 w4 = *(const float4*)(w2 + lane * 4);
    float s = hv.x * w4.x + hv.y * w4.y + hv.z * w4.z + hv.w * w4.w;
#pragma unroll
    for (int d = 1; d < 64; d <<= 1) s += __shfl_xor(s, d);
    if (lane == 0) {
        int b = rowm >> 10, t = rowm & 1023;
        float fs = s + b2[0];
        frame_out[rowm] = (t < lens[b]) ? fs : 0.0f;
    }
}

// ---------------------------------------------------------------------------
__global__ __launch_bounds__(64) void phoneme_kernel(
    const float* __restrict__ frame, const int* __restrict__ plen,
    float* __restrict__ pscore, float* __restrict__ utt,
    float* __restrict__ flu, float* __restrict__ pros)
{
    __shared__ float cs[T_ + 1];
    __shared__ float ps[P_];
    __shared__ int pmk[P_];

    const int b = blockIdx.x;
    const int lane = threadIdx.x;

    float loc[16];
    float run = 0.0f;
#pragma unroll
    for (int i = 0; i < 16; ++i) {
        run += frame[(size_t)b * T_ + lane * 16 + i];
        loc[i] = run;
    }
    float lanesum = run;
    float incl = lanesum;
#pragma unroll
    for (int d = 1; d < 64; d <<= 1) {
        float y = __shfl_up(incl, d);
        if (lane >= d) incl += y;
    }
    float excl = incl - lanesum;
#pragma unroll
    for (int i = 0; i < 16; ++i) cs[lane * 16 + i + 1] = loc[i] + excl;
    if (lane == 0) cs[0] = 0.0f;
    __syncthreads();

    if (lane == 0) {
        int cum = 0, valid = 1;
        float psum = 0.0f;
        int pcnt = 0;
        for (int p = 0; p < P_; ++p) {
            int lp = plen[b * P_ + p];
            if (lp <= 0) valid = 0;
            int eff = valid ? lp : 0;
            int start = cum; if (start > T_) start = T_; if (start < 0) start = 0;
            cum += eff;
            int end = cum; if (end > T_) end = T_; if (end < 0) end = 0;
            int cnt = end - start;
            float score = (cnt > 0) ? (cs[end] - cs[start]) / (float)cnt : 0.0f;
            ps[p] = score;
            pmk[p] = (lp > 0) ? 1 : 0;
            if (lp > 0) { psum += score; pcnt += 1; }
            pscore[b * P_ + p] = score;
        }
        int pc = pcnt > 0 ? pcnt : 1;
        float u = psum / (float)pc;
        float vsum = 0.0f;
        for (int p = 0; p < P_; ++p) {
            float d = ps[p] - u;
            if (pmk[p]) vsum += d * d;
        }
        float pstd = sqrtf(vsum / (float)pc);
        float f = 100.0f - fminf(pstd * 10.0f, 100.0f);
        f = fmaxf(f, 0.0f);
        utt[b] = u;
        flu[b] = f;
        pros[b] = 0.5f * (u + f);
    }
}

// ---------------------------------------------------------------------------
extern "C" void kernel_launch(void* const* d_in, const int* in_sizes, int n_in,
                              void* d_out, int out_size, void* d_ws, size_t ws_size,
                              hipStream_t stream)
{
    const float* features = (const float*)d_in[0];
    const int* feat_len = (const int*)d_in[1];
    const int* plen = (const int*)d_in[2];
    const float* ssl_W = (const float*)d_in[3];
    const float* ssl_b = (const float*)d_in[4];
    const float* ln0_w = (const float*)d_in[5];
    const float* ln0_b = (const float*)d_in[6];
    const float* conv_W = (const float*)d_in[7];
    const float* conv_b = (const float*)d_in[8];
    const float* qkv_W = (const float*)d_in[9];
    const float* qkv_b = (const float*)d_in[10];
    const float* out_W = (const float*)d_in[11];
    const float* out_b = (const float*)d_in[12];
    const float* ln1_w = (const float*)d_in[13];
    const float* ln1_b = (const float*)d_in[14];
    const float* ff1_W = (const float*)d_in[15];
    const float* ff1_b = (const float*)d_in[16];
    const float* ff2_W = (const float*)d_in[17];
    const float* ff2_b = (const float*)d_in[18];
    const float* ln2_w = (const float*)d_in[19];
    const float* ln2_b = (const float*)d_in[20];
    const float* fs1_W = (const float*)d_in[21];
    const float* fs1_b = (const float*)d_in[22];
    const float* fs2_W = (const float*)d_in[23];
    const float* fs2_b = (const float*)d_in[24];

    // ws layout: FFbuf(M*2048) | X(M*256) | Obuf(M*256) | T1(M*256)  ~185MB
    // x512 and QKV alias FFbuf (lifetimes disjoint from FF1 output).
    float* ws = (float*)d_ws;
    float* FFbuf = ws;
    float* X = FFbuf + (size_t)M_ * 2048;
    float* Obuf = X + (size_t)M_ * 256;
    float* T1 = Obuf + (size_t)M_ * 256;
    float* x512 = FFbuf;
    float* QKV = FFbuf;

    float* frame = (float*)d_out;
    float* pscore = frame + M_;
    float* uttp = pscore + B_ * P_;
    float* flup = uttp + B_;
    float* prosp = flup + B_;

    // 1) SSL linear + ReLU, then LN0 (in place)
    gemm_bf16<1><<<dim3(SSL_ / 128, M_ / 128), 256, 0, stream>>>(
        features, ssl_W, ssl_b, x512, M_, SSL_, FIN_);
    ln_kernel<512, 0><<<M_ / 4, 256, 0, stream>>>(x512, nullptr, ln0_w, ln0_b, x512);

    // 2) Conv1d + ReLU -> X
    conv_kernel<<<dim3(4, 16, 16), 256, 0, stream>>>(x512, conv_W, conv_b, X);

    // 3) Transformer layers
    for (int l = 0; l < L_; ++l) {
        gemm_bf16<0><<<dim3(768 / 128, M_ / 128), 256, 0, stream>>>(
            X, qkv_W + (size_t)l * 768 * 256, qkv_b + l * 768, QKV, M_, 768, 256);
        attn_mfma<<<dim3(16, H_, B_), 256, 0, stream>>>(QKV, feat_len, Obuf);
        gemm_bf16<0><<<dim3(256 / 128, M_ / 128), 256, 0, stream>>>(
            Obuf, out_W + (size_t)l * 256 * 256, out_b + l * 256, T1, M_, 256, 256);
        ln_kernel<256, 1><<<M_ / 4, 256, 0, stream>>>(
            T1, X, ln1_w + l * 256, ln1_b + l * 256, X);
        gemm_bf16<1><<<dim3(FF_ / 128, M_ / 128), 256, 0, stream>>>(
            X, ff1_W + (size_t)l * FF_ * 256, ff1_b + l * FF_, FFbuf, M_, FF_, 256);
        gemm_bf16<0><<<dim3(256 / 128, M_ / 128), 256, 0, stream>>>(
            FFbuf, ff2_W + (size_t)l * 256 * FF_, ff2_b + l * 256, T1, M_, 256, FF_);
        ln_kernel<256, 1><<<M_ / 4, 256, 0, stream>>>(
            T1, X, ln2_w + l * 256, ln2_b + l * 256, X);
    }

    // 4) Frame scorer
    gemm_bf16<1><<<dim3(256 / 128, M_ / 128), 256, 0, stream>>>(
        X, fs1_W, fs1_b, T1, M_, 256, 256);
    frame_score_kernel<<<M_ / 4, 256, 0, stream>>>(T1, fs2_W, fs2_b, feat_len, frame);

    // 5) Phoneme/utterance epilogue
    phoneme_kernel<<<B_, 64, 0, stream>>>(frame, plen, pscore, uttp, flup, prosp);
}

// Round 7
// 1058.952 us; speedup vs baseline: 8.2456x; 1.7252x over previous
//
#include <hip/hip_runtime.h>
#include <math.h>

#define B_   16
#define T_   1024
#define FIN_ 1024
#define SSL_ 512
#define D_   256
#define H_   4
#define HD_  64
#define L_   4
#define P_   128
#define FF_  2048
#define M_   (B_ * T_)
#define LN_EPS 1e-5f

typedef __attribute__((ext_vector_type(8))) short bf16x8;
typedef __attribute__((ext_vector_type(4))) float f32x4;

__device__ inline unsigned short f2bf(float f) {
    unsigned int u = __float_as_uint(f);
    u += 0x7fffu + ((u >> 16) & 1u);   // round-to-nearest-even
    return (unsigned short)(u >> 16);
}
__device__ inline float bf2f(unsigned short h) {
    return __uint_as_float(((unsigned int)h) << 16);
}
__device__ inline bf16x8 pack8(float4 a, float4 b) {
    bf16x8 t;
    t[0] = (short)f2bf(a.x); t[1] = (short)f2bf(a.y);
    t[2] = (short)f2bf(a.z); t[3] = (short)f2bf(a.w);
    t[4] = (short)f2bf(b.x); t[5] = (short)f2bf(b.y);
    t[6] = (short)f2bf(b.z); t[7] = (short)f2bf(b.w);
    return t;
}
__device__ inline void glds16(const unsigned short* g, unsigned short* l) {
    __builtin_amdgcn_global_load_lds(
        (const __attribute__((address_space(1))) void*)g,
        (__attribute__((address_space(3))) void*)l, 16, 0, 0);
}

// ---------------------------------------------------------------------------
// fp32 -> bf16 converters (weights + features, run once per launch)
// ---------------------------------------------------------------------------
__global__ __launch_bounds__(256) void cvt_f2b(
    const float* __restrict__ s, unsigned short* __restrict__ d)
{
    size_t i = ((size_t)blockIdx.x * 256 + threadIdx.x) * 8;
    float4 a = *(const float4*)(s + i);
    float4 b = *(const float4*)(s + i + 4);
    *(bf16x8*)(d + i) = pack8(a, b);
}

// conv_W (256,512,3) -> bf16 [kk][n][c]
__global__ __launch_bounds__(256) void cvt_convw(
    const float* __restrict__ s, unsigned short* __restrict__ d)
{
    int i = blockIdx.x * 256 + threadIdx.x;        // 0..393215
    int kk = i >> 17, rem = i & 131071;
    int n = rem >> 9, c = rem & 511;
    d[i] = f2bf(s[(size_t)n * 1536 + c * 3 + kk]);
}

// ---------------------------------------------------------------------------
// bf16 MFMA GEMM (NT), A/B already bf16, staged via global_load_lds dwordx4.
// C[m,n] = relu?( sum_k A[m,k]*W[n,k] + bias[n] ).  Tile 128x128, BK=32,
// 4 waves (2x2 of 64x64, 4x4 frags each).  LDS linear dest; swizzle moved to
// the per-lane GLOBAL source address (inverse of the read-side XOR):
//   physical chunk cp holds logical chunk cp ^ ((row>>1)&3).
// OBF: 0 -> fp32 C, 1 -> bf16 C.
// ---------------------------------------------------------------------------
template <int RELU, int OBF>
__global__ __launch_bounds__(256) void gemm_ll(
    const unsigned short* __restrict__ Ab, const unsigned short* __restrict__ Wb,
    const float* __restrict__ bias, void* __restrict__ Cout,
    int Md, int Nd, int Kd)
{
    __shared__ __align__(16) unsigned short As[128 * 32];
    __shared__ __align__(16) unsigned short Bs[128 * 32];
    char* AsB = (char*)As;
    char* BsB = (char*)Bs;

    const int tid = threadIdx.x;
    const int m0 = blockIdx.y * 128, n0 = blockIdx.x * 128;
    const int w = tid >> 6, l = tid & 63;
    const int lr = l & 15, lg = l >> 4;
    const int wr = w >> 1, wc = w & 1;

    f32x4 acc[4][4];
#pragma unroll
    for (int mi = 0; mi < 4; ++mi)
#pragma unroll
        for (int ni = 0; ni < 4; ++ni) acc[mi][ni] = (f32x4){0.f, 0.f, 0.f, 0.f};

    int aoff[4], boff[4];
#pragma unroll
    for (int mi = 0; mi < 4; ++mi) {
        int row = wr * 64 + mi * 16 + lr;
        aoff[mi] = row * 64 + ((lg * 16) ^ (((row >> 1) & 3) << 4));
    }
#pragma unroll
    for (int ni = 0; ni < 4; ++ni) {
        int row = wc * 64 + ni * 16 + lr;
        boff[ni] = row * 64 + ((lg * 16) ^ (((row >> 1) & 3) << 4));
    }
    // staging geometry: wave w, issue j covers LDS rows [(w*2+j)*16, +16)
    int srow[2], scp[2];
#pragma unroll
    for (int j = 0; j < 2; ++j) {
        int row = (w * 2 + j) * 16 + (l >> 2);
        srow[j] = row;
        scp[j] = (l & 3) ^ ((row >> 1) & 3);
    }

    for (int k0 = 0; k0 < Kd; k0 += 32) {
        __syncthreads();
#pragma unroll
        for (int j = 0; j < 2; ++j) {
            glds16(Ab + (size_t)(m0 + srow[j]) * Kd + k0 + scp[j] * 8,
                   As + (w * 2 + j) * 512);
            glds16(Wb + (size_t)(n0 + srow[j]) * Kd + k0 + scp[j] * 8,
                   Bs + (w * 2 + j) * 512);
        }
        __syncthreads();
        bf16x8 a[4], bb[4];
#pragma unroll
        for (int mi = 0; mi < 4; ++mi) a[mi] = *(bf16x8*)(AsB + aoff[mi]);
#pragma unroll
        for (int ni = 0; ni < 4; ++ni) bb[ni] = *(bf16x8*)(BsB + boff[ni]);
#pragma unroll
        for (int mi = 0; mi < 4; ++mi)
#pragma unroll
            for (int ni = 0; ni < 4; ++ni)
                acc[mi][ni] = __builtin_amdgcn_mfma_f32_16x16x32_bf16(
                    a[mi], bb[ni], acc[mi][ni], 0, 0, 0);
    }

#pragma unroll
    for (int ni = 0; ni < 4; ++ni) {
        int col = n0 + wc * 64 + ni * 16 + lr;
        float bj = bias[col];
#pragma unroll
        for (int mi = 0; mi < 4; ++mi) {
#pragma unroll
            for (int r = 0; r < 4; ++r) {
                int rowg = m0 + wr * 64 + mi * 16 + lg * 4 + r;
                float v = acc[mi][ni][r] + bj;
                if (RELU) v = fmaxf(v, 0.0f);
                if (OBF) {
                    ((unsigned short*)Cout)[(size_t)rowg * Nd + col] = f2bf(v);
                } else {
                    ((float*)Cout)[(size_t)rowg * Nd + col] = v;
                }
            }
        }
    }
}

// ---------------------------------------------------------------------------
// Conv1d k=3 pad=1 as bf16 MFMA: out[m,n] = sum_kk sum_c x[m+kk-1,c]*W[kk,n,c]
// x: (M,512) bf16 (LN0 output), W: [3][256][512] bf16.  Tile 128 m x 128 n,
// A tile = 130 rows (m0-1 .. m0+128) x 32 c; taps read shifted rows.
// Writes X fp32 + Xb bf16 (bias+ReLU fused).
// ---------------------------------------------------------------------------
__global__ __launch_bounds__(256) void conv_mfma(
    const unsigned short* __restrict__ xb, const unsigned short* __restrict__ wb,
    const float* __restrict__ cb, float* __restrict__ X,
    unsigned short* __restrict__ Xb)
{
    __shared__ __align__(16) unsigned short As[130 * 32];
    __shared__ __align__(16) unsigned short Bs[3 * 128 * 32];
    char* AsB = (char*)As;
    char* BsB = (char*)Bs;

    const int tid = threadIdx.x;
    const int n0 = blockIdx.x * 128, m0 = blockIdx.y * 128;
    const int t0 = m0 & 1023;
    const int w = tid >> 6, l = tid & 63;
    const int lr = l & 15, lg = l >> 4;
    const int wr = w >> 1, wc = w & 1;

    f32x4 acc[4][4];
#pragma unroll
    for (int mi = 0; mi < 4; ++mi)
#pragma unroll
        for (int ni = 0; ni < 4; ++ni) acc[mi][ni] = (f32x4){0.f, 0.f, 0.f, 0.f};

    int aoff[4][3], boff[4][3];
#pragma unroll
    for (int mi = 0; mi < 4; ++mi)
#pragma unroll
        for (int kk = 0; kk < 3; ++kk) {
            int row = wr * 64 + mi * 16 + lr + kk;   // local A row (0..129)
            aoff[mi][kk] = row * 64 + ((lg * 16) ^ (((row >> 1) & 3) << 4));
        }
#pragma unroll
    for (int ni = 0; ni < 4; ++ni) {
        int nl = wc * 64 + ni * 16 + lr;
#pragma unroll
        for (int kk = 0; kk < 3; ++kk)
            boff[ni][kk] = kk * 8192 + nl * 64 + ((lg * 16) ^ (((nl >> 1) & 3) << 4));
    }

    for (int c0 = 0; c0 < 512; c0 += 32) {
        __syncthreads();
        // A: 130 rows x 4 chunks = 520 tasks
#pragma unroll
        for (int it = 0; it < 3; ++it) {
            int id = tid + it * 256;
            if (id < 520) {
                int r = id >> 2, ch = id & 3;
                int t = t0 + r - 1;
                bf16x8 v = (bf16x8){0, 0, 0, 0, 0, 0, 0, 0};
                if ((unsigned)t < 1024u)
                    v = *(const bf16x8*)(xb + (size_t)(m0 + r - 1) * 512 + c0 + ch * 8);
                *(bf16x8*)(AsB + r * 64 + ((ch * 16) ^ (((r >> 1) & 3) << 4))) = v;
            }
        }
        // B: 3 taps x 128 n x 4 chunks = 1536 tasks
#pragma unroll
        for (int it = 0; it < 6; ++it) {
            int id = tid + it * 256;
            int kk = id >> 9, rem = id & 511;
            int nl = rem >> 2, ch = rem & 3;
            bf16x8 v = *(const bf16x8*)(wb + (size_t)kk * 131072 +
                                        (size_t)(n0 + nl) * 512 + c0 + ch * 8);
            *(bf16x8*)(BsB + kk * 8192 + nl * 64 +
                       ((ch * 16) ^ (((nl >> 1) & 3) << 4))) = v;
        }
        __syncthreads();
#pragma unroll
        for (int kk = 0; kk < 3; ++kk) {
            bf16x8 bb[4];
#pragma unroll
            for (int ni = 0; ni < 4; ++ni) bb[ni] = *(bf16x8*)(BsB + boff[ni][kk]);
#pragma unroll
            for (int mi = 0; mi < 4; ++mi) {
                bf16x8 a = *(bf16x8*)(AsB + aoff[mi][kk]);
#pragma unroll
                for (int ni = 0; ni < 4; ++ni)
                    acc[mi][ni] = __builtin_amdgcn_mfma_f32_16x16x32_bf16(
                        a, bb[ni], acc[mi][ni], 0, 0, 0);
            }
        }
    }

#pragma unroll
    for (int ni = 0; ni < 4; ++ni) {
        int col = n0 + wc * 64 + ni * 16 + lr;
        float bj = cb[col];
#pragma unroll
        for (int mi = 0; mi < 4; ++mi) {
#pragma unroll
            for (int r = 0; r < 4; ++r) {
                int m = m0 + wr * 64 + mi * 16 + lg * 4 + r;
                float v = fmaxf(acc[mi][ni][r] + bj, 0.0f);
                X[(size_t)m * 256 + col] = v;
                Xb[(size_t)m * 256 + col] = f2bf(v);
            }
        }
    }
}

// ---------------------------------------------------------------------------
// bf16 MFMA flash attention.  qkvb: (B,T,768) bf16 [q|k|v].  Output bf16.
// ---------------------------------------------------------------------------
__global__ __launch_bounds__(256) void attn_mfma(
    const unsigned short* __restrict__ qkvb, const int* __restrict__ lens,
    unsigned short* __restrict__ Ob)
{
    __shared__ __align__(16) unsigned short Kt[64 * 64];     // [k][hd]
    __shared__ __align__(16) unsigned short Vt[64 * 64];     // [d][k]
    __shared__ __align__(16) unsigned short Pt[4][16 * 64];  // per-wave [q][k]

    const int qt = blockIdx.x, h = blockIdx.y, b = blockIdx.z;
    const int tid = threadIdx.x;
    const int w = tid >> 6, l = tid & 63;
    const int lr = l & 15, lg = l >> 4;
    const int len = lens[b];
    const size_t base = (size_t)b * (T_ * 768);
    const int q0 = qt * 64 + w * 16;

    char* KtB = (char*)Kt;
    char* VtB = (char*)Vt;
    char* PtB = (char*)(Pt[w]);

    bf16x8 qf[2];
#pragma unroll
    for (int half = 0; half < 2; ++half)
        qf[half] = *(const bf16x8*)(qkvb + base + (size_t)(q0 + lr) * 768 +
                                    h * 64 + lg * 8 + half * 32);

    float mrun = -3e38f, lrun = 0.0f;
    f32x4 acc_o[4];
#pragma unroll
    for (int td = 0; td < 4; ++td) acc_o[td] = (f32x4){0.f, 0.f, 0.f, 0.f};

    int skr[2], skc[2];
#pragma unroll
    for (int jj = 0; jj < 2; ++jj) {
        int id = tid + jj * 256;
        skr[jj] = id >> 3; skc[jj] = id & 7;
    }

    for (int tk = 0; tk < 16; ++tk) {
        const int kv0 = tk * 64;
        __syncthreads();
#pragma unroll
        for (int jj = 0; jj < 2; ++jj) {
            int kr = skr[jj], c = skc[jj];
            const unsigned short* kp =
                qkvb + base + (size_t)(kv0 + kr) * 768 + h * 64 + 256 + c * 8;
            *(bf16x8*)(KtB + kr * 128 + ((c << 4) ^ ((kr & 7) << 4))) =
                *(const bf16x8*)kp;
            bf16x8 vv = *(const bf16x8*)(kp + 256);
#pragma unroll
            for (int j = 0; j < 8; ++j) {
                int d = c * 8 + j;
                *(unsigned short*)(VtB + d * 128 + ((kr * 2) ^ ((d & 7) << 4))) =
                    (unsigned short)vv[j];
            }
        }
        __syncthreads();

        f32x4 accs[4];
#pragma unroll
        for (int kt = 0; kt < 4; ++kt) {
            int row = kt * 16 + lr;
            int rb = row * 128, sw = (row & 7) << 4;
            bf16x8 k0 = *(bf16x8*)(KtB + rb + ((lg * 16) ^ sw));
            bf16x8 k1 = *(bf16x8*)(KtB + rb + ((lg * 16 + 64) ^ sw));
            f32x4 z = (f32x4){0.f, 0.f, 0.f, 0.f};
            f32x4 t = __builtin_amdgcn_mfma_f32_16x16x32_bf16(k0, qf[0], z, 0, 0, 0);
            accs[kt] = __builtin_amdgcn_mfma_f32_16x16x32_bf16(k1, qf[1], t, 0, 0, 0);
        }

        float p[16];
        float pmax = -3e38f;
#pragma unroll
        for (int kt = 0; kt < 4; ++kt)
#pragma unroll
            for (int r = 0; r < 4; ++r) {
                int kidx = kv0 + kt * 16 + lg * 4 + r;
                float v = (kidx < len) ? accs[kt][r] * 0.125f : -1e30f;
                p[kt * 4 + r] = v;
                pmax = fmaxf(pmax, v);
            }
        pmax = fmaxf(pmax, __shfl_xor(pmax, 16));
        pmax = fmaxf(pmax, __shfl_xor(pmax, 32));
        float mnew = fmaxf(mrun, pmax);
        float alpha = __expf(mrun - mnew);
        float psum = 0.0f;
#pragma unroll
        for (int i = 0; i < 16; ++i) {
            float e = __expf(p[i] - mnew);
            p[i] = e;
            psum += e;
        }
        psum += __shfl_xor(psum, 16);
        psum += __shfl_xor(psum, 32);
        lrun = lrun * alpha + psum;
        mrun = mnew;
#pragma unroll
        for (int td = 0; td < 4; ++td) acc_o[td] *= alpha;

        const int swq = (lr & 7) << 4;
#pragma unroll
        for (int kt = 0; kt < 4; ++kt) {
            unsigned int p01 = (unsigned int)f2bf(p[kt * 4 + 0]) |
                               ((unsigned int)f2bf(p[kt * 4 + 1]) << 16);
            unsigned int p23 = (unsigned int)f2bf(p[kt * 4 + 2]) |
                               ((unsigned int)f2bf(p[kt * 4 + 3]) << 16);
            uint2 pw; pw.x = p01; pw.y = p23;
            *(uint2*)(PtB + lr * 128 + ((kt * 32 + lg * 8) ^ swq)) = pw;
        }
        bf16x8 pf0 = *(bf16x8*)(PtB + lr * 128 + ((lg * 16) ^ swq));
        bf16x8 pf1 = *(bf16x8*)(PtB + lr * 128 + ((lg * 16 + 64) ^ swq));
#pragma unroll
        for (int td = 0; td < 4; ++td) {
            int d = td * 16 + lr;
            int db = d * 128, swd = (d & 7) << 4;
            bf16x8 v0 = *(bf16x8*)(VtB + db + ((lg * 16) ^ swd));
            bf16x8 v1 = *(bf16x8*)(VtB + db + ((lg * 16 + 64) ^ swd));
            acc_o[td] = __builtin_amdgcn_mfma_f32_16x16x32_bf16(v0, pf0, acc_o[td], 0, 0, 0);
            acc_o[td] = __builtin_amdgcn_mfma_f32_16x16x32_bf16(v1, pf1, acc_o[td], 0, 0, 0);
        }
    }

    float inv = 1.0f / lrun;
    const int tglob = qt * 64 + w * 16 + lr;
#pragma unroll
    for (int td = 0; td < 4; ++td)
#pragma unroll
        for (int r = 0; r < 4; ++r) {
            int d = td * 16 + lg * 4 + r;
            Ob[((size_t)b * T_ + tglob) * 256 + h * 64 + d] = f2bf(acc_o[td][r] * inv);
        }
}

// ---------------------------------------------------------------------------
// LN0: bf16 in (M,512), bf16 out, no residual.  One wave per row.
// ---------------------------------------------------------------------------
__global__ __launch_bounds__(256) void ln0_bf16(
    const unsigned short* __restrict__ xin, const float* __restrict__ w,
    const float* __restrict__ b, unsigned short* __restrict__ out)
{
    const int lane = threadIdx.x & 63;
    const int wv = threadIdx.x >> 6;
    const int row = blockIdx.x * 4 + wv;

    bf16x8 v8 = *(const bf16x8*)(xin + (size_t)row * 512 + lane * 8);
    float f[8];
    float s = 0.0f, sq = 0.0f;
#pragma unroll
    for (int j = 0; j < 8; ++j) {
        f[j] = bf2f((unsigned short)v8[j]);
        s += f[j];
        sq += f[j] * f[j];
    }
#pragma unroll
    for (int d = 1; d < 64; d <<= 1) {
        s += __shfl_xor(s, d);
        sq += __shfl_xor(sq, d);
    }
    float mean = s / 512.0f;
    float var = fmaxf(sq / 512.0f - mean * mean, 0.0f);
    float inv = 1.0f / sqrtf(var + LN_EPS);
    float4 w0 = *(const float4*)(w + lane * 8);
    float4 w1 = *(const float4*)(w + lane * 8 + 4);
    float4 b0 = *(const float4*)(b + lane * 8);
    float4 b1 = *(const float4*)(b + lane * 8 + 4);
    float wv8[8] = {w0.x, w0.y, w0.z, w0.w, w1.x, w1.y, w1.z, w1.w};
    float bv8[8] = {b0.x, b0.y, b0.z, b0.w, b1.x, b1.y, b1.z, b1.w};
    bf16x8 o;
#pragma unroll
    for (int j = 0; j < 8; ++j)
        o[j] = (short)f2bf((f[j] - mean) * inv * wv8[j] + bv8[j]);
    *(bf16x8*)(out + (size_t)row * 512 + lane * 8) = o;
}

// ---------------------------------------------------------------------------
// LN (W=256) with residual; writes fp32 out AND bf16 outb.
// ---------------------------------------------------------------------------
__global__ __launch_bounds__(256) void ln_res_dual(
    const float* __restrict__ xin, const float* __restrict__ resid,
    const float* __restrict__ w, const float* __restrict__ b,
    float* __restrict__ out, unsigned short* __restrict__ outb)
{
    const int lane = threadIdx.x & 63;
    const int wv = threadIdx.x >> 6;
    const int row = blockIdx.x * 4 + wv;

    float4 t = *(const float4*)(xin + (size_t)row * 256 + lane * 4);
    float4 r4 = *(const float4*)(resid + (size_t)row * 256 + lane * 4);
    t.x += r4.x; t.y += r4.y; t.z += r4.z; t.w += r4.w;
    float s = t.x + t.y + t.z + t.w;
    float sq = t.x * t.x + t.y * t.y + t.z * t.z + t.w * t.w;
#pragma unroll
    for (int d = 1; d < 64; d <<= 1) {
        s += __shfl_xor(s, d);
        sq += __shfl_xor(sq, d);
    }
    float mean = s / 256.0f;
    float var = fmaxf(sq / 256.0f - mean * mean, 0.0f);
    float inv = 1.0f / sqrtf(var + LN_EPS);
    float4 wc = *(const float4*)(w + lane * 4);
    float4 bc = *(const float4*)(b + lane * 4);
    float4 o;
    o.x = (t.x - mean) * inv * wc.x + bc.x;
    o.y = (t.y - mean) * inv * wc.y + bc.y;
    o.z = (t.z - mean) * inv * wc.z + bc.z;
    o.w = (t.w - mean) * inv * wc.w + bc.w;
    *(float4*)(out + (size_t)row * 256 + lane * 4) = o;
    uint2 ob;
    ob.x = (unsigned int)f2bf(o.x) | ((unsigned int)f2bf(o.y) << 16);
    ob.y = (unsigned int)f2bf(o.z) | ((unsigned int)f2bf(o.w) << 16);
    *(uint2*)(outb + (size_t)row * 256 + lane * 4) = ob;
}

// ---------------------------------------------------------------------------
__global__ __launch_bounds__(256) void frame_score_kernel(
    const float* __restrict__ hbuf, const float* __restrict__ w2,
    const float* __restrict__ b2, const int* __restrict__ lens,
    float* __restrict__ frame_out)
{
    const int lane = threadIdx.x & 63;
    const int wv = threadIdx.x >> 6;
    const int rowm = blockIdx.x * 4 + wv;
    float4 hv = *(const float4*)(hbuf + (size_t)rowm * 256 + lane * 4);
    float4 w4 = *(const float4*)(w2 + lane * 4);
    float s = hv.x * w4.x + hv.y * w4.y + hv.z * w4.z + hv.w * w4.w;
#pragma unroll
    for (int d = 1; d < 64; d <<= 1) s += __shfl_xor(s, d);
    if (lane == 0) {
        int b = rowm >> 10, t = rowm & 1023;
        float fs = s + b2[0];
        frame_out[rowm] = (t < lens[b]) ? fs : 0.0f;
    }
}

// ---------------------------------------------------------------------------
__global__ __launch_bounds__(64) void phoneme_kernel(
    const float* __restrict__ frame, const int* __restrict__ plen,
    float* __restrict__ pscore, float* __restrict__ utt,
    float* __restrict__ flu, float* __restrict__ pros)
{
    __shared__ float cs[T_ + 1];
    __shared__ float ps[P_];
    __shared__ int pmk[P_];

    const int b = blockIdx.x;
    const int lane = threadIdx.x;

    float loc[16];
    float run = 0.0f;
#pragma unroll
    for (int i = 0; i < 16; ++i) {
        run += frame[(size_t)b * T_ + lane * 16 + i];
        loc[i] = run;
    }
    float lanesum = run;
    float incl = lanesum;
#pragma unroll
    for (int d = 1; d < 64; d <<= 1) {
        float y = __shfl_up(incl, d);
        if (lane >= d) incl += y;
    }
    float excl = incl - lanesum;
#pragma unroll
    for (int i = 0; i < 16; ++i) cs[lane * 16 + i + 1] = loc[i] + excl;
    if (lane == 0) cs[0] = 0.0f;
    __syncthreads();

    if (lane == 0) {
        int cum = 0, valid = 1;
        float psum = 0.0f;
        int pcnt = 0;
        for (int p = 0; p < P_; ++p) {
            int lp = plen[b * P_ + p];
            if (lp <= 0) valid = 0;
            int eff = valid ? lp : 0;
            int start = cum; if (start > T_) start = T_; if (start < 0) start = 0;
            cum += eff;
            int end = cum; if (end > T_) end = T_; if (end < 0) end = 0;
            int cnt = end - start;
            float score = (cnt > 0) ? (cs[end] - cs[start]) / (float)cnt : 0.0f;
            ps[p] = score;
            pmk[p] = (lp > 0) ? 1 : 0;
            if (lp > 0) { psum += score; pcnt += 1; }
            pscore[b * P_ + p] = score;
        }
        int pc = pcnt > 0 ? pcnt : 1;
        float u = psum / (float)pc;
        float vsum = 0.0f;
        for (int p = 0; p < P_; ++p) {
            float d = ps[p] - u;
            if (pmk[p]) vsum += d * d;
        }
        float pstd = sqrtf(vsum / (float)pc);
        float f = 100.0f - fminf(pstd * 10.0f, 100.0f);
        f = fmaxf(f, 0.0f);
        utt[b] = u;
        flu[b] = f;
        pros[b] = 0.5f * (u + f);
    }
}

// ---------------------------------------------------------------------------
extern "C" void kernel_launch(void* const* d_in, const int* in_sizes, int n_in,
                              void* d_out, int out_size, void* d_ws, size_t ws_size,
                              hipStream_t stream)
{
    const float* features = (const float*)d_in[0];
    const int* feat_len = (const int*)d_in[1];
    const int* plen = (const int*)d_in[2];
    const float* ssl_W = (const float*)d_in[3];
    const float* ssl_b = (const float*)d_in[4];
    const float* ln0_w = (const float*)d_in[5];
    const float* ln0_b = (const float*)d_in[6];
    const float* conv_W = (const float*)d_in[7];
    const float* conv_b = (const float*)d_in[8];
    const float* qkv_W = (const float*)d_in[9];
    const float* qkv_b = (const float*)d_in[10];
    const float* out_W = (const float*)d_in[11];
    const float* out_b = (const float*)d_in[12];
    const float* ln1_w = (const float*)d_in[13];
    const float* ln1_b = (const float*)d_in[14];
    const float* ff1_W = (const float*)d_in[15];
    const float* ff1_b = (const float*)d_in[16];
    const float* ff2_W = (const float*)d_in[17];
    const float* ff2_b = (const float*)d_in[18];
    const float* ln2_w = (const float*)d_in[19];
    const float* ln2_b = (const float*)d_in[20];
    const float* fs1_W = (const float*)d_in[21];
    const float* fs1_b = (const float*)d_in[22];
    const float* fs2_W = (const float*)d_in[23];
    const float* fs2_b = (const float*)d_in[24];

    // --- workspace layout (~155 MB) ---
    char* base = (char*)d_ws;
    unsigned short* FFb = (unsigned short*)base;               // M*2048 bf16
    unsigned short* featb = FFb;                               // alias (M*1024)
    unsigned short* QKVb = (unsigned short*)(base + (size_t)M_ * 2048 * 2);  // M*768
    unsigned short* x512b = QKVb;                              // alias (M*512)
    float* X = (float*)(base + (size_t)M_ * 2048 * 2 + (size_t)M_ * 768 * 2);
    unsigned short* Xb = (unsigned short*)((char*)X + (size_t)M_ * 256 * 4);
    unsigned short* Ob = Xb + (size_t)M_ * 256;
    float* T1 = (float*)((char*)Ob + (size_t)M_ * 256 * 2);
    unsigned short* sslWb = (unsigned short*)((char*)T1 + (size_t)M_ * 256 * 4);
    unsigned short* convWb = sslWb + 512 * 1024;
    unsigned short* qkvWb = convWb + 3 * 256 * 512;
    unsigned short* outWb = qkvWb + (size_t)L_ * 768 * 256;
    unsigned short* ff1Wb = outWb + (size_t)L_ * 256 * 256;
    unsigned short* ff2Wb = ff1Wb + (size_t)L_ * 2048 * 256;
    unsigned short* fs1Wb = ff2Wb + (size_t)L_ * 256 * 2048;

    float* frame = (float*)d_out;
    float* pscore = frame + M_;
    float* uttp = pscore + B_ * P_;
    float* flup = uttp + B_;
    float* prosp = flup + B_;

    // 0) convert weights + features to bf16
    cvt_f2b<<<8192, 256, 0, stream>>>(features, featb);
    cvt_f2b<<<256, 256, 0, stream>>>(ssl_W, sslWb);
    cvt_convw<<<1536, 256, 0, stream>>>(conv_W, convWb);
    cvt_f2b<<<384, 256, 0, stream>>>(qkv_W, qkvWb);
    cvt_f2b<<<128, 256, 0, stream>>>(out_W, outWb);
    cvt_f2b<<<1024, 256, 0, stream>>>(ff1_W, ff1Wb);
    cvt_f2b<<<1024, 256, 0, stream>>>(ff2_W, ff2Wb);
    cvt_f2b<<<32, 256, 0, stream>>>(fs1_W, fs1Wb);

    // 1) SSL linear + ReLU -> x512b (bf16), then LN0 in place
    gemm_ll<1, 1><<<dim3(SSL_ / 128, M_ / 128), 256, 0, stream>>>(
        featb, sslWb, ssl_b, x512b, M_, SSL_, FIN_);
    ln0_bf16<<<M_ / 4, 256, 0, stream>>>(x512b, ln0_w, ln0_b, x512b);

    // 2) Conv1d + ReLU -> X (fp32) + Xb (bf16)
    conv_mfma<<<dim3(2, M_ / 128), 256, 0, stream>>>(x512b, convWb, conv_b, X, Xb);

    // 3) Transformer layers
    for (int l = 0; l < L_; ++l) {
        gemm_ll<0, 1><<<dim3(768 / 128, M_ / 128), 256, 0, stream>>>(
            Xb, qkvWb + (size_t)l * 768 * 256, qkv_b + l * 768, QKVb, M_, 768, 256);
        attn_mfma<<<dim3(16, H_, B_), 256, 0, stream>>>(QKVb, feat_len, Ob);
        gemm_ll<0, 0><<<dim3(256 / 128, M_ / 128), 256, 0, stream>>>(
            Ob, outWb + (size_t)l * 256 * 256, out_b + l * 256, T1, M_, 256, 256);
        ln_res_dual<<<M_ / 4, 256, 0, stream>>>(
            T1, X, ln1_w + l * 256, ln1_b + l * 256, X, Xb);
        gemm_ll<1, 1><<<dim3(FF_ / 128, M_ / 128), 256, 0, stream>>>(
            Xb, ff1Wb + (size_t)l * FF_ * 256, ff1_b + l * FF_, FFb, M_, FF_, 256);
        gemm_ll<0, 0><<<dim3(256 / 128, M_ / 128), 256, 0, stream>>>(
            FFb, ff2Wb + (size_t)l * 256 * FF_, ff2_b + l * 256, T1, M_, 256, FF_);
        ln_res_dual<<<M_ / 4, 256, 0, stream>>>(
            T1, X, ln2_w + l * 256, ln2_b + l * 256, X, Xb);
    }

    // 4) Frame scorer
    gemm_ll<1, 0><<<dim3(256 / 128, M_ / 128), 256, 0, stream>>>(
        Xb, fs1Wb, fs1_b, T1, M_, 256, 256);
    frame_score_kernel<<<M_ / 4, 256, 0, stream>>>(T1, fs2_W, fs2_b, feat_len, frame);

    // 5) Phoneme/utterance epilogue
    phoneme_kernel<<<B_, 64, 0, stream>>>(frame, plen, pscore, uttp, flup, prosp);
}

// Round 8
// 979.293 us; speedup vs baseline: 8.9163x; 1.0813x over previous
//
#include <hip/hip_runtime.h>
#include <math.h>

#define B_   16
#define T_   1024
#define FIN_ 1024
#define SSL_ 512
#define D_   256
#define H_   4
#define HD_  64
#define L_   4
#define P_   128
#define FF_  2048
#define M_   (B_ * T_)
#define LN_EPS 1e-5f

typedef __attribute__((ext_vector_type(8))) short bf16x8;
typedef __attribute__((ext_vector_type(4))) float f32x4;

__device__ inline unsigned short f2bf(float f) {
    unsigned int u = __float_as_uint(f);
    u += 0x7fffu + ((u >> 16) & 1u);   // round-to-nearest-even
    return (unsigned short)(u >> 16);
}
__device__ inline float bf2f(unsigned short h) {
    return __uint_as_float(((unsigned int)h) << 16);
}
__device__ inline bf16x8 pack8(float4 a, float4 b) {
    bf16x8 t;
    t[0] = (short)f2bf(a.x); t[1] = (short)f2bf(a.y);
    t[2] = (short)f2bf(a.z); t[3] = (short)f2bf(a.w);
    t[4] = (short)f2bf(b.x); t[5] = (short)f2bf(b.y);
    t[6] = (short)f2bf(b.z); t[7] = (short)f2bf(b.w);
    return t;
}
__device__ inline void glds16(const unsigned short* g, unsigned short* l) {
    __builtin_amdgcn_global_load_lds(
        (const __attribute__((address_space(1))) void*)g,
        (__attribute__((address_space(3))) void*)l, 16, 0, 0);
}

// ---------------------------------------------------------------------------
// fp32 -> bf16 converters (weights + features, run once per launch)
// ---------------------------------------------------------------------------
__global__ __launch_bounds__(256) void cvt_f2b(
    const float* __restrict__ s, unsigned short* __restrict__ d)
{
    size_t i = ((size_t)blockIdx.x * 256 + threadIdx.x) * 8;
    float4 a = *(const float4*)(s + i);
    float4 b = *(const float4*)(s + i + 4);
    *(bf16x8*)(d + i) = pack8(a, b);
}

// conv_W (256,512,3) -> bf16 [kk][n][c]
__global__ __launch_bounds__(256) void cvt_convw(
    const float* __restrict__ s, unsigned short* __restrict__ d)
{
    int i = blockIdx.x * 256 + threadIdx.x;        // 0..393215
    int kk = i >> 17, rem = i & 131071;
    int n = rem >> 9, c = rem & 511;
    d[i] = f2bf(s[(size_t)n * 1536 + c * 3 + kk]);
}

// ---------------------------------------------------------------------------
// bf16 MFMA GEMM (NT), A/B already bf16, staged via global_load_lds dwordx4.
// C[m,n] = relu?( sum_k A[m,k]*W[n,k] + bias[n] ).  Tile 128x128, BK=32,
// 4 waves (2x2 of 64x64, 4x4 frags each).  LDS linear dest; swizzle moved to
// the per-lane GLOBAL source address (inverse of the read-side XOR).
// OBF: 0 -> fp32 C, 1 -> bf16 C.
// ---------------------------------------------------------------------------
template <int RELU, int OBF>
__global__ __launch_bounds__(256) void gemm_ll(
    const unsigned short* __restrict__ Ab, const unsigned short* __restrict__ Wb,
    const float* __restrict__ bias, void* __restrict__ Cout,
    int Md, int Nd, int Kd)
{
    __shared__ __align__(16) unsigned short As[128 * 32];
    __shared__ __align__(16) unsigned short Bs[128 * 32];
    char* AsB = (char*)As;
    char* BsB = (char*)Bs;

    const int tid = threadIdx.x;
    const int m0 = blockIdx.y * 128, n0 = blockIdx.x * 128;
    const int w = tid >> 6, l = tid & 63;
    const int lr = l & 15, lg = l >> 4;
    const int wr = w >> 1, wc = w & 1;

    f32x4 acc[4][4];
#pragma unroll
    for (int mi = 0; mi < 4; ++mi)
#pragma unroll
        for (int ni = 0; ni < 4; ++ni) acc[mi][ni] = (f32x4){0.f, 0.f, 0.f, 0.f};

    int aoff[4], boff[4];
#pragma unroll
    for (int mi = 0; mi < 4; ++mi) {
        int row = wr * 64 + mi * 16 + lr;
        aoff[mi] = row * 64 + ((lg * 16) ^ (((row >> 1) & 3) << 4));
    }
#pragma unroll
    for (int ni = 0; ni < 4; ++ni) {
        int row = wc * 64 + ni * 16 + lr;
        boff[ni] = row * 64 + ((lg * 16) ^ (((row >> 1) & 3) << 4));
    }
    // staging geometry: wave w, issue j covers LDS rows [(w*2+j)*16, +16)
    int srow[2], scp[2];
#pragma unroll
    for (int j = 0; j < 2; ++j) {
        int row = (w * 2 + j) * 16 + (l >> 2);
        srow[j] = row;
        scp[j] = (l & 3) ^ ((row >> 1) & 3);
    }

    for (int k0 = 0; k0 < Kd; k0 += 32) {
        __syncthreads();
#pragma unroll
        for (int j = 0; j < 2; ++j) {
            glds16(Ab + (size_t)(m0 + srow[j]) * Kd + k0 + scp[j] * 8,
                   As + (w * 2 + j) * 512);
            glds16(Wb + (size_t)(n0 + srow[j]) * Kd + k0 + scp[j] * 8,
                   Bs + (w * 2 + j) * 512);
        }
        __syncthreads();
        bf16x8 a[4], bb[4];
#pragma unroll
        for (int mi = 0; mi < 4; ++mi) a[mi] = *(bf16x8*)(AsB + aoff[mi]);
#pragma unroll
        for (int ni = 0; ni < 4; ++ni) bb[ni] = *(bf16x8*)(BsB + boff[ni]);
#pragma unroll
        for (int mi = 0; mi < 4; ++mi)
#pragma unroll
            for (int ni = 0; ni < 4; ++ni)
                acc[mi][ni] = __builtin_amdgcn_mfma_f32_16x16x32_bf16(
                    a[mi], bb[ni], acc[mi][ni], 0, 0, 0);
    }

#pragma unroll
    for (int ni = 0; ni < 4; ++ni) {
        int col = n0 + wc * 64 + ni * 16 + lr;
        float bj = bias[col];
#pragma unroll
        for (int mi = 0; mi < 4; ++mi) {
#pragma unroll
            for (int r = 0; r < 4; ++r) {
                int rowg = m0 + wr * 64 + mi * 16 + lg * 4 + r;
                float v = acc[mi][ni][r] + bj;
                if (RELU) v = fmaxf(v, 0.0f);
                if (OBF) {
                    ((unsigned short*)Cout)[(size_t)rowg * Nd + col] = f2bf(v);
                } else {
                    ((float*)Cout)[(size_t)rowg * Nd + col] = v;
                }
            }
        }
    }
}

// ---------------------------------------------------------------------------
// Conv1d k=3 pad=1 as bf16 MFMA (unchanged from round 7)
// ---------------------------------------------------------------------------
__global__ __launch_bounds__(256) void conv_mfma(
    const unsigned short* __restrict__ xb, const unsigned short* __restrict__ wb,
    const float* __restrict__ cb, float* __restrict__ X,
    unsigned short* __restrict__ Xb)
{
    __shared__ __align__(16) unsigned short As[130 * 32];
    __shared__ __align__(16) unsigned short Bs[3 * 128 * 32];
    char* AsB = (char*)As;
    char* BsB = (char*)Bs;

    const int tid = threadIdx.x;
    const int n0 = blockIdx.x * 128, m0 = blockIdx.y * 128;
    const int t0 = m0 & 1023;
    const int w = tid >> 6, l = tid & 63;
    const int lr = l & 15, lg = l >> 4;
    const int wr = w >> 1, wc = w & 1;

    f32x4 acc[4][4];
#pragma unroll
    for (int mi = 0; mi < 4; ++mi)
#pragma unroll
        for (int ni = 0; ni < 4; ++ni) acc[mi][ni] = (f32x4){0.f, 0.f, 0.f, 0.f};

    int aoff[4][3], boff[4][3];
#pragma unroll
    for (int mi = 0; mi < 4; ++mi)
#pragma unroll
        for (int kk = 0; kk < 3; ++kk) {
            int row = wr * 64 + mi * 16 + lr + kk;   // local A row (0..129)
            aoff[mi][kk] = row * 64 + ((lg * 16) ^ (((row >> 1) & 3) << 4));
        }
#pragma unroll
    for (int ni = 0; ni < 4; ++ni) {
        int nl = wc * 64 + ni * 16 + lr;
#pragma unroll
        for (int kk = 0; kk < 3; ++kk)
            boff[ni][kk] = kk * 8192 + nl * 64 + ((lg * 16) ^ (((nl >> 1) & 3) << 4));
    }

    for (int c0 = 0; c0 < 512; c0 += 32) {
        __syncthreads();
        // A: 130 rows x 4 chunks = 520 tasks
#pragma unroll
        for (int it = 0; it < 3; ++it) {
            int id = tid + it * 256;
            if (id < 520) {
                int r = id >> 2, ch = id & 3;
                int t = t0 + r - 1;
                bf16x8 v = (bf16x8){0, 0, 0, 0, 0, 0, 0, 0};
                if ((unsigned)t < 1024u)
                    v = *(const bf16x8*)(xb + (size_t)(m0 + r - 1) * 512 + c0 + ch * 8);
                *(bf16x8*)(AsB + r * 64 + ((ch * 16) ^ (((r >> 1) & 3) << 4))) = v;
            }
        }
        // B: 3 taps x 128 n x 4 chunks = 1536 tasks
#pragma unroll
        for (int it = 0; it < 6; ++it) {
            int id = tid + it * 256;
            int kk = id >> 9, rem = id & 511;
            int nl = rem >> 2, ch = rem & 3;
            bf16x8 v = *(const bf16x8*)(wb + (size_t)kk * 131072 +
                                        (size_t)(n0 + nl) * 512 + c0 + ch * 8);
            *(bf16x8*)(BsB + kk * 8192 + nl * 64 +
                       ((ch * 16) ^ (((nl >> 1) & 3) << 4))) = v;
        }
        __syncthreads();
#pragma unroll
        for (int kk = 0; kk < 3; ++kk) {
            bf16x8 bb[4];
#pragma unroll
            for (int ni = 0; ni < 4; ++ni) bb[ni] = *(bf16x8*)(BsB + boff[ni][kk]);
#pragma unroll
            for (int mi = 0; mi < 4; ++mi) {
                bf16x8 a = *(bf16x8*)(AsB + aoff[mi][kk]);
#pragma unroll
                for (int ni = 0; ni < 4; ++ni)
                    acc[mi][ni] = __builtin_amdgcn_mfma_f32_16x16x32_bf16(
                        a, bb[ni], acc[mi][ni], 0, 0, 0);
            }
        }
    }

#pragma unroll
    for (int ni = 0; ni < 4; ++ni) {
        int col = n0 + wc * 64 + ni * 16 + lr;
        float bj = cb[col];
#pragma unroll
        for (int mi = 0; mi < 4; ++mi) {
#pragma unroll
            for (int r = 0; r < 4; ++r) {
                int m = m0 + wr * 64 + mi * 16 + lg * 4 + r;
                float v = fmaxf(acc[mi][ni][r] + bj, 0.0f);
                X[(size_t)m * 256 + col] = v;
                Xb[(size_t)m * 256 + col] = f2bf(v);
            }
        }
    }
}

// ---------------------------------------------------------------------------
// bf16 MFMA flash attention, 128 q-rows/block (8 waves, 512 thr).
// qkvb: (B,T,768) bf16 [q|k|v].  Output bf16.
// Changes vs r7: 2x q-tile (halves K/V staging + V-transpose per q-row),
// len-aware tile skip (masked tiles contribute exact 0), setprio on MFMA.
// ---------------------------------------------------------------------------
__global__ __launch_bounds__(512) void attn_mfma(
    const unsigned short* __restrict__ qkvb, const int* __restrict__ lens,
    unsigned short* __restrict__ Ob)
{
    __shared__ __align__(16) unsigned short Kt[64 * 64];     // [k][hd]
    __shared__ __align__(16) unsigned short Vt[64 * 64];     // [d][k]
    __shared__ __align__(16) unsigned short Pt[8][16 * 64];  // per-wave [q][k]

    const int qt = blockIdx.x, h = blockIdx.y, b = blockIdx.z;
    const int tid = threadIdx.x;
    const int w = tid >> 6, l = tid & 63;
    const int lr = l & 15, lg = l >> 4;
    const int len = lens[b];
    const int nt = (len + 63) >> 6;          // tiles with any valid k (<= 16)
    const size_t base = (size_t)b * (T_ * 768);
    const int q0 = qt * 128 + w * 16;

    char* KtB = (char*)Kt;
    char* VtB = (char*)Vt;
    char* PtB = (char*)(Pt[w]);

    bf16x8 qf[2];
#pragma unroll
    for (int half = 0; half < 2; ++half)
        qf[half] = *(const bf16x8*)(qkvb + base + (size_t)(q0 + lr) * 768 +
                                    h * 64 + lg * 8 + half * 32);

    float mrun = -3e38f, lrun = 0.0f;
    f32x4 acc_o[4];
#pragma unroll
    for (int td = 0; td < 4; ++td) acc_o[td] = (f32x4){0.f, 0.f, 0.f, 0.f};

    // staging: 512 tasks (64 k-rows x 8 chunks), exactly 1 per thread
    const int skr = tid >> 3, skc = tid & 7;

    for (int tk = 0; tk < nt; ++tk) {
        const int kv0 = tk * 64;
        __syncthreads();
        {
            const unsigned short* kp =
                qkvb + base + (size_t)(kv0 + skr) * 768 + h * 64 + 256 + skc * 8;
            *(bf16x8*)(KtB + skr * 128 + ((skc << 4) ^ ((skr & 7) << 4))) =
                *(const bf16x8*)kp;
            bf16x8 vv = *(const bf16x8*)(kp + 256);
#pragma unroll
            for (int j = 0; j < 8; ++j) {
                int d = skc * 8 + j;
                *(unsigned short*)(VtB + d * 128 + ((skr * 2) ^ ((d & 7) << 4))) =
                    (unsigned short)vv[j];
            }
        }
        __syncthreads();

        f32x4 accs[4];
        __builtin_amdgcn_s_setprio(1);
#pragma unroll
        for (int kt = 0; kt < 4; ++kt) {
            int row = kt * 16 + lr;
            int rb = row * 128, sw = (row & 7) << 4;
            bf16x8 k0 = *(bf16x8*)(KtB + rb + ((lg * 16) ^ sw));
            bf16x8 k1 = *(bf16x8*)(KtB + rb + ((lg * 16 + 64) ^ sw));
            f32x4 z = (f32x4){0.f, 0.f, 0.f, 0.f};
            f32x4 t = __builtin_amdgcn_mfma_f32_16x16x32_bf16(k0, qf[0], z, 0, 0, 0);
            accs[kt] = __builtin_amdgcn_mfma_f32_16x16x32_bf16(k1, qf[1], t, 0, 0, 0);
        }
        __builtin_amdgcn_s_setprio(0);

        float p[16];
        float pmax = -3e38f;
#pragma unroll
        for (int kt = 0; kt < 4; ++kt)
#pragma unroll
            for (int r = 0; r < 4; ++r) {
                int kidx = kv0 + kt * 16 + lg * 4 + r;
                float v = (kidx < len) ? accs[kt][r] * 0.125f : -1e30f;
                p[kt * 4 + r] = v;
                pmax = fmaxf(pmax, v);
            }
        pmax = fmaxf(pmax, __shfl_xor(pmax, 16));
        pmax = fmaxf(pmax, __shfl_xor(pmax, 32));
        float mnew = fmaxf(mrun, pmax);
        float alpha = __expf(mrun - mnew);
        float psum = 0.0f;
#pragma unroll
        for (int i = 0; i < 16; ++i) {
            float e = __expf(p[i] - mnew);
            p[i] = e;
            psum += e;
        }
        psum += __shfl_xor(psum, 16);
        psum += __shfl_xor(psum, 32);
        lrun = lrun * alpha + psum;
        mrun = mnew;
#pragma unroll
        for (int td = 0; td < 4; ++td) acc_o[td] *= alpha;

        const int swq = (lr & 7) << 4;
#pragma unroll
        for (int kt = 0; kt < 4; ++kt) {
            unsigned int p01 = (unsigned int)f2bf(p[kt * 4 + 0]) |
                               ((unsigned int)f2bf(p[kt * 4 + 1]) << 16);
            unsigned int p23 = (unsigned int)f2bf(p[kt * 4 + 2]) |
                               ((unsigned int)f2bf(p[kt * 4 + 3]) << 16);
            uint2 pw; pw.x = p01; pw.y = p23;
            *(uint2*)(PtB + lr * 128 + ((kt * 32 + lg * 8) ^ swq)) = pw;
        }
        bf16x8 pf0 = *(bf16x8*)(PtB + lr * 128 + ((lg * 16) ^ swq));
        bf16x8 pf1 = *(bf16x8*)(PtB + lr * 128 + ((lg * 16 + 64) ^ swq));
        __builtin_amdgcn_s_setprio(1);
#pragma unroll
        for (int td = 0; td < 4; ++td) {
            int d = td * 16 + lr;
            int db = d * 128, swd = (d & 7) << 4;
            bf16x8 v0 = *(bf16x8*)(VtB + db + ((lg * 16) ^ swd));
            bf16x8 v1 = *(bf16x8*)(VtB + db + ((lg * 16 + 64) ^ swd));
            acc_o[td] = __builtin_amdgcn_mfma_f32_16x16x32_bf16(v0, pf0, acc_o[td], 0, 0, 0);
            acc_o[td] = __builtin_amdgcn_mfma_f32_16x16x32_bf16(v1, pf1, acc_o[td], 0, 0, 0);
        }
        __builtin_amdgcn_s_setprio(0);
    }

    float inv = 1.0f / lrun;
    const int tglob = q0 + lr;
#pragma unroll
    for (int td = 0; td < 4; ++td)
#pragma unroll
        for (int r = 0; r < 4; ++r) {
            int d = td * 16 + lg * 4 + r;
            Ob[((size_t)b * T_ + tglob) * 256 + h * 64 + d] = f2bf(acc_o[td][r] * inv);
        }
}

// ---------------------------------------------------------------------------
// LN0: bf16 in (M,512), bf16 out, no residual.  One wave per row.
// ---------------------------------------------------------------------------
__global__ __launch_bounds__(256) void ln0_bf16(
    const unsigned short* __restrict__ xin, const float* __restrict__ w,
    const float* __restrict__ b, unsigned short* __restrict__ out)
{
    const int lane = threadIdx.x & 63;
    const int wv = threadIdx.x >> 6;
    const int row = blockIdx.x * 4 + wv;

    bf16x8 v8 = *(const bf16x8*)(xin + (size_t)row * 512 + lane * 8);
    float f[8];
    float s = 0.0f, sq = 0.0f;
#pragma unroll
    for (int j = 0; j < 8; ++j) {
        f[j] = bf2f((unsigned short)v8[j]);
        s += f[j];
        sq += f[j] * f[j];
    }
#pragma unroll
    for (int d = 1; d < 64; d <<= 1) {
        s += __shfl_xor(s, d);
        sq += __shfl_xor(sq, d);
    }
    float mean = s / 512.0f;
    float var = fmaxf(sq / 512.0f - mean * mean, 0.0f);
    float inv = 1.0f / sqrtf(var + LN_EPS);
    float4 w0 = *(const float4*)(w + lane * 8);
    float4 w1 = *(const float4*)(w + lane * 8 + 4);
    float4 b0 = *(const float4*)(b + lane * 8);
    float4 b1 = *(const float4*)(b + lane * 8 + 4);
    float wv8[8] = {w0.x, w0.y, w0.z, w0.w, w1.x, w1.y, w1.z, w1.w};
    float bv8[8] = {b0.x, b0.y, b0.z, b0.w, b1.x, b1.y, b1.z, b1.w};
    bf16x8 o;
#pragma unroll
    for (int j = 0; j < 8; ++j)
        o[j] = (short)f2bf((f[j] - mean) * inv * wv8[j] + bv8[j]);
    *(bf16x8*)(out + (size_t)row * 512 + lane * 8) = o;
}

// ---------------------------------------------------------------------------
// LN (W=256) with residual; writes fp32 out AND bf16 outb.
// ---------------------------------------------------------------------------
__global__ __launch_bounds__(256) void ln_res_dual(
    const float* __restrict__ xin, const float* __restrict__ resid,
    const float* __restrict__ w, const float* __restrict__ b,
    float* __restrict__ out, unsigned short* __restrict__ outb)
{
    const int lane = threadIdx.x & 63;
    const int wv = threadIdx.x >> 6;
    const int row = blockIdx.x * 4 + wv;

    float4 t = *(const float4*)(xin + (size_t)row * 256 + lane * 4);
    float4 r4 = *(const float4*)(resid + (size_t)row * 256 + lane * 4);
    t.x += r4.x; t.y += r4.y; t.z += r4.z; t.w += r4.w;
    float s = t.x + t.y + t.z + t.w;
    float sq = t.x * t.x + t.y * t.y + t.z * t.z + t.w * t.w;
#pragma unroll
    for (int d = 1; d < 64; d <<= 1) {
        s += __shfl_xor(s, d);
        sq += __shfl_xor(sq, d);
    }
    float mean = s / 256.0f;
    float var = fmaxf(sq / 256.0f - mean * mean, 0.0f);
    float inv = 1.0f / sqrtf(var + LN_EPS);
    float4 wc = *(const float4*)(w + lane * 4);
    float4 bc = *(const float4*)(b + lane * 4);
    float4 o;
    o.x = (t.x - mean) * inv * wc.x + bc.x;
    o.y = (t.y - mean) * inv * wc.y + bc.y;
    o.z = (t.z - mean) * inv * wc.z + bc.z;
    o.w = (t.w - mean) * inv * wc.w + bc.w;
    *(float4*)(out + (size_t)row * 256 + lane * 4) = o;
    uint2 ob;
    ob.x = (unsigned int)f2bf(o.x) | ((unsigned int)f2bf(o.y) << 16);
    ob.y = (unsigned int)f2bf(o.z) | ((unsigned int)f2bf(o.w) << 16);
    *(uint2*)(outb + (size_t)row * 256 + lane * 4) = ob;
}

// ---------------------------------------------------------------------------
__global__ __launch_bounds__(256) void frame_score_kernel(
    const float* __restrict__ hbuf, const float* __restrict__ w2,
    const float* __restrict__ b2, const int* __restrict__ lens,
    float* __restrict__ frame_out)
{
    const int lane = threadIdx.x & 63;
    const int wv = threadIdx.x >> 6;
    const int rowm = blockIdx.x * 4 + wv;
    float4 hv = *(const float4*)(hbuf + (size_t)rowm * 256 + lane * 4);
    float4 w4 = *(const float4*)(w2 + lane * 4);
    float s = hv.x * w4.x + hv.y * w4.y + hv.z * w4.z + hv.w * w4.w;
#pragma unroll
    for (int d = 1; d < 64; d <<= 1) s += __shfl_xor(s, d);
    if (lane == 0) {
        int b = rowm >> 10, t = rowm & 1023;
        float fs = s + b2[0];
        frame_out[rowm] = (t < lens[b]) ? fs : 0.0f;
    }
}

// ---------------------------------------------------------------------------
__global__ __launch_bounds__(64) void phoneme_kernel(
    const float* __restrict__ frame, const int* __restrict__ plen,
    float* __restrict__ pscore, float* __restrict__ utt,
    float* __restrict__ flu, float* __restrict__ pros)
{
    __shared__ float cs[T_ + 1];
    __shared__ float ps[P_];
    __shared__ int pmk[P_];

    const int b = blockIdx.x;
    const int lane = threadIdx.x;

    float loc[16];
    float run = 0.0f;
#pragma unroll
    for (int i = 0; i < 16; ++i) {
        run += frame[(size_t)b * T_ + lane * 16 + i];
        loc[i] = run;
    }
    float lanesum = run;
    float incl = lanesum;
#pragma unroll
    for (int d = 1; d < 64; d <<= 1) {
        float y = __shfl_up(incl, d);
        if (lane >= d) incl += y;
    }
    float excl = incl - lanesum;
#pragma unroll
    for (int i = 0; i < 16; ++i) cs[lane * 16 + i + 1] = loc[i] + excl;
    if (lane == 0) cs[0] = 0.0f;
    __syncthreads();

    if (lane == 0) {
        int cum = 0, valid = 1;
        float psum = 0.0f;
        int pcnt = 0;
        for (int p = 0; p < P_; ++p) {
            int lp = plen[b * P_ + p];
            if (lp <= 0) valid = 0;
            int eff = valid ? lp : 0;
            int start = cum; if (start > T_) start = T_; if (start < 0) start = 0;
            cum += eff;
            int end = cum; if (end > T_) end = T_; if (end < 0) end = 0;
            int cnt = end - start;
            float score = (cnt > 0) ? (cs[end] - cs[start]) / (float)cnt : 0.0f;
            ps[p] = score;
            pmk[p] = (lp > 0) ? 1 : 0;
            if (lp > 0) { psum += score; pcnt += 1; }
            pscore[b * P_ + p] = score;
        }
        int pc = pcnt > 0 ? pcnt : 1;
        float u = psum / (float)pc;
        float vsum = 0.0f;
        for (int p = 0; p < P_; ++p) {
            float d = ps[p] - u;
            if (pmk[p]) vsum += d * d;
        }
        float pstd = sqrtf(vsum / (float)pc);
        float f = 100.0f - fminf(pstd * 10.0f, 100.0f);
        f = fmaxf(f, 0.0f);
        utt[b] = u;
        flu[b] = f;
        pros[b] = 0.5f * (u + f);
    }
}

// ---------------------------------------------------------------------------
extern "C" void kernel_launch(void* const* d_in, const int* in_sizes, int n_in,
                              void* d_out, int out_size, void* d_ws, size_t ws_size,
                              hipStream_t stream)
{
    const float* features = (const float*)d_in[0];
    const int* feat_len = (const int*)d_in[1];
    const int* plen = (const int*)d_in[2];
    const float* ssl_W = (const float*)d_in[3];
    const float* ssl_b = (const float*)d_in[4];
    const float* ln0_w = (const float*)d_in[5];
    const float* ln0_b = (const float*)d_in[6];
    const float* conv_W = (const float*)d_in[7];
    const float* conv_b = (const float*)d_in[8];
    const float* qkv_W = (const float*)d_in[9];
    const float* qkv_b = (const float*)d_in[10];
    const float* out_W = (const float*)d_in[11];
    const float* out_b = (const float*)d_in[12];
    const float* ln1_w = (const float*)d_in[13];
    const float* ln1_b = (const float*)d_in[14];
    const float* ff1_W = (const float*)d_in[15];
    const float* ff1_b = (const float*)d_in[16];
    const float* ff2_W = (const float*)d_in[17];
    const float* ff2_b = (const float*)d_in[18];
    const float* ln2_w = (const float*)d_in[19];
    const float* ln2_b = (const float*)d_in[20];
    const float* fs1_W = (const float*)d_in[21];
    const float* fs1_b = (const float*)d_in[22];
    const float* fs2_W = (const float*)d_in[23];
    const float* fs2_b = (const float*)d_in[24];

    // --- workspace layout (~155 MB) ---
    char* base = (char*)d_ws;
    unsigned short* FFb = (unsigned short*)base;               // M*2048 bf16
    unsigned short* featb = FFb;                               // alias (M*1024)
    unsigned short* QKVb = (unsigned short*)(base + (size_t)M_ * 2048 * 2);  // M*768
    unsigned short* x512b = QKVb;                              // alias (M*512)
    float* X = (float*)(base + (size_t)M_ * 2048 * 2 + (size_t)M_ * 768 * 2);
    unsigned short* Xb = (unsigned short*)((char*)X + (size_t)M_ * 256 * 4);
    unsigned short* Ob = Xb + (size_t)M_ * 256;
    float* T1 = (float*)((char*)Ob + (size_t)M_ * 256 * 2);
    unsigned short* sslWb = (unsigned short*)((char*)T1 + (size_t)M_ * 256 * 4);
    unsigned short* convWb = sslWb + 512 * 1024;
    unsigned short* qkvWb = convWb + 3 * 256 * 512;
    unsigned short* outWb = qkvWb + (size_t)L_ * 768 * 256;
    unsigned short* ff1Wb = outWb + (size_t)L_ * 256 * 256;
    unsigned short* ff2Wb = ff1Wb + (size_t)L_ * 2048 * 256;
    unsigned short* fs1Wb = ff2Wb + (size_t)L_ * 256 * 2048;

    float* frame = (float*)d_out;
    float* pscore = frame + M_;
    float* uttp = pscore + B_ * P_;
    float* flup = uttp + B_;
    float* prosp = flup + B_;

    // 0) convert weights + features to bf16
    cvt_f2b<<<8192, 256, 0, stream>>>(features, featb);
    cvt_f2b<<<256, 256, 0, stream>>>(ssl_W, sslWb);
    cvt_convw<<<1536, 256, 0, stream>>>(conv_W, convWb);
    cvt_f2b<<<384, 256, 0, stream>>>(qkv_W, qkvWb);
    cvt_f2b<<<128, 256, 0, stream>>>(out_W, outWb);
    cvt_f2b<<<1024, 256, 0, stream>>>(ff1_W, ff1Wb);
    cvt_f2b<<<1024, 256, 0, stream>>>(ff2_W, ff2Wb);
    cvt_f2b<<<32, 256, 0, stream>>>(fs1_W, fs1Wb);

    // 1) SSL linear + ReLU -> x512b (bf16), then LN0 in place
    gemm_ll<1, 1><<<dim3(SSL_ / 128, M_ / 128), 256, 0, stream>>>(
        featb, sslWb, ssl_b, x512b, M_, SSL_, FIN_);
    ln0_bf16<<<M_ / 4, 256, 0, stream>>>(x512b, ln0_w, ln0_b, x512b);

    // 2) Conv1d + ReLU -> X (fp32) + Xb (bf16)
    conv_mfma<<<dim3(2, M_ / 128), 256, 0, stream>>>(x512b, convWb, conv_b, X, Xb);

    // 3) Transformer layers
    for (int l = 0; l < L_; ++l) {
        gemm_ll<0, 1><<<dim3(768 / 128, M_ / 128), 256, 0, stream>>>(
            Xb, qkvWb + (size_t)l * 768 * 256, qkv_b + l * 768, QKVb, M_, 768, 256);
        attn_mfma<<<dim3(8, H_, B_), 512, 0, stream>>>(QKVb, feat_len, Ob);
        gemm_ll<0, 0><<<dim3(256 / 128, M_ / 128), 256, 0, stream>>>(
            Ob, outWb + (size_t)l * 256 * 256, out_b + l * 256, T1, M_, 256, 256);
        ln_res_dual<<<M_ / 4, 256, 0, stream>>>(
            T1, X, ln1_w + l * 256, ln1_b + l * 256, X, Xb);
        gemm_ll<1, 1><<<dim3(FF_ / 128, M_ / 128), 256, 0, stream>>>(
            Xb, ff1Wb + (size_t)l * FF_ * 256, ff1_b + l * FF_, FFb, M_, FF_, 256);
        gemm_ll<0, 0><<<dim3(256 / 128, M_ / 128), 256, 0, stream>>>(
            FFb, ff2Wb + (size_t)l * 256 * FF_, ff2_b + l * 256, T1, M_, 256, FF_);
        ln_res_dual<<<M_ / 4, 256, 0, stream>>>(
            T1, X, ln2_w + l * 256, ln2_b + l * 256, X, Xb);
    }

    // 4) Frame scorer
    gemm_ll<1, 0><<<dim3(256 / 128, M_ / 128), 256, 0, stream>>>(
        Xb, fs1Wb, fs1_b, T1, M_, 256, 256);
    frame_score_kernel<<<M_ / 4, 256, 0, stream>>>(T1, fs2_W, fs2_b, feat_len, frame);

    // 5) Phoneme/utterance epilogue
    phoneme_kernel<<<B_, 64, 0, stream>>>(frame, plen, pscore, uttp, flup, prosp);
}

// Round 9
// 933.637 us; speedup vs baseline: 9.3523x; 1.0489x over previous
//
#include <hip/hip_runtime.h>
#include <math.h>

#define B_   16
#define T_   1024
#define FIN_ 1024
#define SSL_ 512
#define D_   256
#define H_   4
#define HD_  64
#define L_   4
#define P_   128
#define FF_  2048
#define M_   (B_ * T_)
#define LN_EPS 1e-5f

typedef __attribute__((ext_vector_type(8))) short bf16x8;
typedef __attribute__((ext_vector_type(4))) float f32x4;

__device__ inline unsigned short f2bf(float f) {
    unsigned int u = __float_as_uint(f);
    u += 0x7fffu + ((u >> 16) & 1u);   // round-to-nearest-even
    return (unsigned short)(u >> 16);
}
__device__ inline float bf2f(unsigned short h) {
    return __uint_as_float(((unsigned int)h) << 16);
}
__device__ inline bf16x8 pack8(float4 a, float4 b) {
    bf16x8 t;
    t[0] = (short)f2bf(a.x); t[1] = (short)f2bf(a.y);
    t[2] = (short)f2bf(a.z); t[3] = (short)f2bf(a.w);
    t[4] = (short)f2bf(b.x); t[5] = (short)f2bf(b.y);
    t[6] = (short)f2bf(b.z); t[7] = (short)f2bf(b.w);
    return t;
}
__device__ inline void glds16(const unsigned short* g, unsigned short* l) {
    __builtin_amdgcn_global_load_lds(
        (const __attribute__((address_space(1))) void*)g,
        (__attribute__((address_space(3))) void*)l, 16, 0, 0);
}

// ---------------------------------------------------------------------------
// fp32 -> bf16 converters (weights + features, run once per launch)
// ---------------------------------------------------------------------------
__global__ __launch_bounds__(256) void cvt_f2b(
    const float* __restrict__ s, unsigned short* __restrict__ d)
{
    size_t i = ((size_t)blockIdx.x * 256 + threadIdx.x) * 8;
    float4 a = *(const float4*)(s + i);
    float4 b = *(const float4*)(s + i + 4);
    *(bf16x8*)(d + i) = pack8(a, b);
}

// conv_W (256,512,3) -> bf16 [kk][n][c]
__global__ __launch_bounds__(256) void cvt_convw(
    const float* __restrict__ s, unsigned short* __restrict__ d)
{
    int i = blockIdx.x * 256 + threadIdx.x;        // 0..393215
    int kk = i >> 17, rem = i & 131071;
    int n = rem >> 9, c = rem & 511;
    d[i] = f2bf(s[(size_t)n * 1536 + c * 3 + kk]);
}

// ---------------------------------------------------------------------------
// bf16 MFMA GEMM (NT), A/B already bf16, staged via global_load_lds dwordx4.
// C[m,n] = relu?( sum_k A[m,k]*W[n,k] + bias[n] ).  Tile 128x128, BK=32,
// 4 waves (2x2 of 64x64, 4x4 frags each).  LDS linear dest; swizzle moved to
// the per-lane GLOBAL source address (inverse of the read-side XOR).
// OBF: 0 -> fp32 C, 1 -> bf16 C.
// ---------------------------------------------------------------------------
template <int RELU, int OBF>
__global__ __launch_bounds__(256) void gemm_ll(
    const unsigned short* __restrict__ Ab, const unsigned short* __restrict__ Wb,
    const float* __restrict__ bias, void* __restrict__ Cout,
    int Md, int Nd, int Kd)
{
    __shared__ __align__(16) unsigned short As[128 * 32];
    __shared__ __align__(16) unsigned short Bs[128 * 32];
    char* AsB = (char*)As;
    char* BsB = (char*)Bs;

    const int tid = threadIdx.x;
    const int m0 = blockIdx.y * 128, n0 = blockIdx.x * 128;
    const int w = tid >> 6, l = tid & 63;
    const int lr = l & 15, lg = l >> 4;
    const int wr = w >> 1, wc = w & 1;

    f32x4 acc[4][4];
#pragma unroll
    for (int mi = 0; mi < 4; ++mi)
#pragma unroll
        for (int ni = 0; ni < 4; ++ni) acc[mi][ni] = (f32x4){0.f, 0.f, 0.f, 0.f};

    int aoff[4], boff[4];
#pragma unroll
    for (int mi = 0; mi < 4; ++mi) {
        int row = wr * 64 + mi * 16 + lr;
        aoff[mi] = row * 64 + ((lg * 16) ^ (((row >> 1) & 3) << 4));
    }
#pragma unroll
    for (int ni = 0; ni < 4; ++ni) {
        int row = wc * 64 + ni * 16 + lr;
        boff[ni] = row * 64 + ((lg * 16) ^ (((row >> 1) & 3) << 4));
    }
    // staging geometry: wave w, issue j covers LDS rows [(w*2+j)*16, +16)
    int srow[2], scp[2];
#pragma unroll
    for (int j = 0; j < 2; ++j) {
        int row = (w * 2 + j) * 16 + (l >> 2);
        srow[j] = row;
        scp[j] = (l & 3) ^ ((row >> 1) & 3);
    }

    for (int k0 = 0; k0 < Kd; k0 += 32) {
        __syncthreads();
#pragma unroll
        for (int j = 0; j < 2; ++j) {
            glds16(Ab + (size_t)(m0 + srow[j]) * Kd + k0 + scp[j] * 8,
                   As + (w * 2 + j) * 512);
            glds16(Wb + (size_t)(n0 + srow[j]) * Kd + k0 + scp[j] * 8,
                   Bs + (w * 2 + j) * 512);
        }
        __syncthreads();
        bf16x8 a[4], bb[4];
#pragma unroll
        for (int mi = 0; mi < 4; ++mi) a[mi] = *(bf16x8*)(AsB + aoff[mi]);
#pragma unroll
        for (int ni = 0; ni < 4; ++ni) bb[ni] = *(bf16x8*)(BsB + boff[ni]);
#pragma unroll
        for (int mi = 0; mi < 4; ++mi)
#pragma unroll
            for (int ni = 0; ni < 4; ++ni)
                acc[mi][ni] = __builtin_amdgcn_mfma_f32_16x16x32_bf16(
                    a[mi], bb[ni], acc[mi][ni], 0, 0, 0);
    }

#pragma unroll
    for (int ni = 0; ni < 4; ++ni) {
        int col = n0 + wc * 64 + ni * 16 + lr;
        float bj = bias[col];
#pragma unroll
        for (int mi = 0; mi < 4; ++mi) {
#pragma unroll
            for (int r = 0; r < 4; ++r) {
                int rowg = m0 + wr * 64 + mi * 16 + lg * 4 + r;
                float v = acc[mi][ni][r] + bj;
                if (RELU) v = fmaxf(v, 0.0f);
                if (OBF) {
                    ((unsigned short*)Cout)[(size_t)rowg * Nd + col] = f2bf(v);
                } else {
                    ((float*)Cout)[(size_t)rowg * Nd + col] = v;
                }
            }
        }
    }
}

// ---------------------------------------------------------------------------
// Conv1d k=3 pad=1 as bf16 MFMA.  Writes ONLY bf16 Xb (bias+ReLU fused).
// ---------------------------------------------------------------------------
__global__ __launch_bounds__(256) void conv_mfma(
    const unsigned short* __restrict__ xb, const unsigned short* __restrict__ wb,
    const float* __restrict__ cb, unsigned short* __restrict__ Xb)
{
    __shared__ __align__(16) unsigned short As[130 * 32];
    __shared__ __align__(16) unsigned short Bs[3 * 128 * 32];
    char* AsB = (char*)As;
    char* BsB = (char*)Bs;

    const int tid = threadIdx.x;
    const int n0 = blockIdx.x * 128, m0 = blockIdx.y * 128;
    const int t0 = m0 & 1023;
    const int w = tid >> 6, l = tid & 63;
    const int lr = l & 15, lg = l >> 4;
    const int wr = w >> 1, wc = w & 1;

    f32x4 acc[4][4];
#pragma unroll
    for (int mi = 0; mi < 4; ++mi)
#pragma unroll
        for (int ni = 0; ni < 4; ++ni) acc[mi][ni] = (f32x4){0.f, 0.f, 0.f, 0.f};

    int aoff[4][3], boff[4][3];
#pragma unroll
    for (int mi = 0; mi < 4; ++mi)
#pragma unroll
        for (int kk = 0; kk < 3; ++kk) {
            int row = wr * 64 + mi * 16 + lr + kk;   // local A row (0..129)
            aoff[mi][kk] = row * 64 + ((lg * 16) ^ (((row >> 1) & 3) << 4));
        }
#pragma unroll
    for (int ni = 0; ni < 4; ++ni) {
        int nl = wc * 64 + ni * 16 + lr;
#pragma unroll
        for (int kk = 0; kk < 3; ++kk)
            boff[ni][kk] = kk * 8192 + nl * 64 + ((lg * 16) ^ (((nl >> 1) & 3) << 4));
    }

    for (int c0 = 0; c0 < 512; c0 += 32) {
        __syncthreads();
        // A: 130 rows x 4 chunks = 520 tasks
#pragma unroll
        for (int it = 0; it < 3; ++it) {
            int id = tid + it * 256;
            if (id < 520) {
                int r = id >> 2, ch = id & 3;
                int t = t0 + r - 1;
                bf16x8 v = (bf16x8){0, 0, 0, 0, 0, 0, 0, 0};
                if ((unsigned)t < 1024u)
                    v = *(const bf16x8*)(xb + (size_t)(m0 + r - 1) * 512 + c0 + ch * 8);
                *(bf16x8*)(AsB + r * 64 + ((ch * 16) ^ (((r >> 1) & 3) << 4))) = v;
            }
        }
        // B: 3 taps x 128 n x 4 chunks = 1536 tasks
#pragma unroll
        for (int it = 0; it < 6; ++it) {
            int id = tid + it * 256;
            int kk = id >> 9, rem = id & 511;
            int nl = rem >> 2, ch = rem & 3;
            bf16x8 v = *(const bf16x8*)(wb + (size_t)kk * 131072 +
                                        (size_t)(n0 + nl) * 512 + c0 + ch * 8);
            *(bf16x8*)(BsB + kk * 8192 + nl * 64 +
                       ((ch * 16) ^ (((nl >> 1) & 3) << 4))) = v;
        }
        __syncthreads();
#pragma unroll
        for (int kk = 0; kk < 3; ++kk) {
            bf16x8 bb[4];
#pragma unroll
            for (int ni = 0; ni < 4; ++ni) bb[ni] = *(bf16x8*)(BsB + boff[ni][kk]);
#pragma unroll
            for (int mi = 0; mi < 4; ++mi) {
                bf16x8 a = *(bf16x8*)(AsB + aoff[mi][kk]);
#pragma unroll
                for (int ni = 0; ni < 4; ++ni)
                    acc[mi][ni] = __builtin_amdgcn_mfma_f32_16x16x32_bf16(
                        a, bb[ni], acc[mi][ni], 0, 0, 0);
            }
        }
    }

#pragma unroll
    for (int ni = 0; ni < 4; ++ni) {
        int col = n0 + wc * 64 + ni * 16 + lr;
        float bj = cb[col];
#pragma unroll
        for (int mi = 0; mi < 4; ++mi) {
#pragma unroll
            for (int r = 0; r < 4; ++r) {
                int m = m0 + wr * 64 + mi * 16 + lg * 4 + r;
                float v = fmaxf(acc[mi][ni][r] + bj, 0.0f);
                Xb[(size_t)m * 256 + col] = f2bf(v);
            }
        }
    }
}

// ---------------------------------------------------------------------------
// bf16 MFMA flash attention, 128 q-rows/block (8 waves, 512 thr).
// Unchanged from round 8.
// ---------------------------------------------------------------------------
__global__ __launch_bounds__(512) void attn_mfma(
    const unsigned short* __restrict__ qkvb, const int* __restrict__ lens,
    unsigned short* __restrict__ Ob)
{
    __shared__ __align__(16) unsigned short Kt[64 * 64];     // [k][hd]
    __shared__ __align__(16) unsigned short Vt[64 * 64];     // [d][k]
    __shared__ __align__(16) unsigned short Pt[8][16 * 64];  // per-wave [q][k]

    const int qt = blockIdx.x, h = blockIdx.y, b = blockIdx.z;
    const int tid = threadIdx.x;
    const int w = tid >> 6, l = tid & 63;
    const int lr = l & 15, lg = l >> 4;
    const int len = lens[b];
    const int nt = (len + 63) >> 6;          // tiles with any valid k (<= 16)
    const size_t base = (size_t)b * (T_ * 768);
    const int q0 = qt * 128 + w * 16;

    char* KtB = (char*)Kt;
    char* VtB = (char*)Vt;
    char* PtB = (char*)(Pt[w]);

    bf16x8 qf[2];
#pragma unroll
    for (int half = 0; half < 2; ++half)
        qf[half] = *(const bf16x8*)(qkvb + base + (size_t)(q0 + lr) * 768 +
                                    h * 64 + lg * 8 + half * 32);

    float mrun = -3e38f, lrun = 0.0f;
    f32x4 acc_o[4];
#pragma unroll
    for (int td = 0; td < 4; ++td) acc_o[td] = (f32x4){0.f, 0.f, 0.f, 0.f};

    // staging: 512 tasks (64 k-rows x 8 chunks), exactly 1 per thread
    const int skr = tid >> 3, skc = tid & 7;

    for (int tk = 0; tk < nt; ++tk) {
        const int kv0 = tk * 64;
        __syncthreads();
        {
            const unsigned short* kp =
                qkvb + base + (size_t)(kv0 + skr) * 768 + h * 64 + 256 + skc * 8;
            *(bf16x8*)(KtB + skr * 128 + ((skc << 4) ^ ((skr & 7) << 4))) =
                *(const bf16x8*)kp;
            bf16x8 vv = *(const bf16x8*)(kp + 256);
#pragma unroll
            for (int j = 0; j < 8; ++j) {
                int d = skc * 8 + j;
                *(unsigned short*)(VtB + d * 128 + ((skr * 2) ^ ((d & 7) << 4))) =
                    (unsigned short)vv[j];
            }
        }
        __syncthreads();

        f32x4 accs[4];
        __builtin_amdgcn_s_setprio(1);
#pragma unroll
        for (int kt = 0; kt < 4; ++kt) {
            int row = kt * 16 + lr;
            int rb = row * 128, sw = (row & 7) << 4;
            bf16x8 k0 = *(bf16x8*)(KtB + rb + ((lg * 16) ^ sw));
            bf16x8 k1 = *(bf16x8*)(KtB + rb + ((lg * 16 + 64) ^ sw));
            f32x4 z = (f32x4){0.f, 0.f, 0.f, 0.f};
            f32x4 t = __builtin_amdgcn_mfma_f32_16x16x32_bf16(k0, qf[0], z, 0, 0, 0);
            accs[kt] = __builtin_amdgcn_mfma_f32_16x16x32_bf16(k1, qf[1], t, 0, 0, 0);
        }
        __builtin_amdgcn_s_setprio(0);

        float p[16];
        float pmax = -3e38f;
#pragma unroll
        for (int kt = 0; kt < 4; ++kt)
#pragma unroll
            for (int r = 0; r < 4; ++r) {
                int kidx = kv0 + kt * 16 + lg * 4 + r;
                float v = (kidx < len) ? accs[kt][r] * 0.125f : -1e30f;
                p[kt * 4 + r] = v;
                pmax = fmaxf(pmax, v);
            }
        pmax = fmaxf(pmax, __shfl_xor(pmax, 16));
        pmax = fmaxf(pmax, __shfl_xor(pmax, 32));
        float mnew = fmaxf(mrun, pmax);
        float alpha = __expf(mrun - mnew);
        float psum = 0.0f;
#pragma unroll
        for (int i = 0; i < 16; ++i) {
            float e = __expf(p[i] - mnew);
            p[i] = e;
            psum += e;
        }
        psum += __shfl_xor(psum, 16);
        psum += __shfl_xor(psum, 32);
        lrun = lrun * alpha + psum;
        mrun = mnew;
#pragma unroll
        for (int td = 0; td < 4; ++td) acc_o[td] *= alpha;

        const int swq = (lr & 7) << 4;
#pragma unroll
        for (int kt = 0; kt < 4; ++kt) {
            unsigned int p01 = (unsigned int)f2bf(p[kt * 4 + 0]) |
                               ((unsigned int)f2bf(p[kt * 4 + 1]) << 16);
            unsigned int p23 = (unsigned int)f2bf(p[kt * 4 + 2]) |
                               ((unsigned int)f2bf(p[kt * 4 + 3]) << 16);
            uint2 pw; pw.x = p01; pw.y = p23;
            *(uint2*)(PtB + lr * 128 + ((kt * 32 + lg * 8) ^ swq)) = pw;
        }
        bf16x8 pf0 = *(bf16x8*)(PtB + lr * 128 + ((lg * 16) ^ swq));
        bf16x8 pf1 = *(bf16x8*)(PtB + lr * 128 + ((lg * 16 + 64) ^ swq));
        __builtin_amdgcn_s_setprio(1);
#pragma unroll
        for (int td = 0; td < 4; ++td) {
            int d = td * 16 + lr;
            int db = d * 128, swd = (d & 7) << 4;
            bf16x8 v0 = *(bf16x8*)(VtB + db + ((lg * 16) ^ swd));
            bf16x8 v1 = *(bf16x8*)(VtB + db + ((lg * 16 + 64) ^ swd));
            acc_o[td] = __builtin_amdgcn_mfma_f32_16x16x32_bf16(v0, pf0, acc_o[td], 0, 0, 0);
            acc_o[td] = __builtin_amdgcn_mfma_f32_16x16x32_bf16(v1, pf1, acc_o[td], 0, 0, 0);
        }
        __builtin_amdgcn_s_setprio(0);
    }

    float inv = 1.0f / lrun;
    const int tglob = q0 + lr;
#pragma unroll
    for (int td = 0; td < 4; ++td)
#pragma unroll
        for (int r = 0; r < 4; ++r) {
            int d = td * 16 + lg * 4 + r;
            Ob[((size_t)b * T_ + tglob) * 256 + h * 64 + d] = f2bf(acc_o[td][r] * inv);
        }
}

// ---------------------------------------------------------------------------
// LN0: bf16 in (M,512), bf16 out, no residual.  One wave per row.
// ---------------------------------------------------------------------------
__global__ __launch_bounds__(256) void ln0_bf16(
    const unsigned short* __restrict__ xin, const float* __restrict__ w,
    const float* __restrict__ b, unsigned short* __restrict__ out)
{
    const int lane = threadIdx.x & 63;
    const int wv = threadIdx.x >> 6;
    const int row = blockIdx.x * 4 + wv;

    bf16x8 v8 = *(const bf16x8*)(xin + (size_t)row * 512 + lane * 8);
    float f[8];
    float s = 0.0f, sq = 0.0f;
#pragma unroll
    for (int j = 0; j < 8; ++j) {
        f[j] = bf2f((unsigned short)v8[j]);
        s += f[j];
        sq += f[j] * f[j];
    }
#pragma unroll
    for (int d = 1; d < 64; d <<= 1) {
        s += __shfl_xor(s, d);
        sq += __shfl_xor(sq, d);
    }
    float mean = s / 512.0f;
    float var = fmaxf(sq / 512.0f - mean * mean, 0.0f);
    float inv = 1.0f / sqrtf(var + LN_EPS);
    float4 w0 = *(const float4*)(w + lane * 8);
    float4 w1 = *(const float4*)(w + lane * 8 + 4);
    float4 b0 = *(const float4*)(b + lane * 8);
    float4 b1 = *(const float4*)(b + lane * 8 + 4);
    float wv8[8] = {w0.x, w0.y, w0.z, w0.w, w1.x, w1.y, w1.z, w1.w};
    float bv8[8] = {b0.x, b0.y, b0.z, b0.w, b1.x, b1.y, b1.z, b1.w};
    bf16x8 o;
#pragma unroll
    for (int j = 0; j < 8; ++j)
        o[j] = (short)f2bf((f[j] - mean) * inv * wv8[j] + bv8[j]);
    *(bf16x8*)(out + (size_t)row * 512 + lane * 8) = o;
}

// ---------------------------------------------------------------------------
// LN (W=256), all-bf16: out = LN(t1 + resid) -> bf16.  One wave per row.
// ---------------------------------------------------------------------------
__global__ __launch_bounds__(256) void ln_res_bf16(
    const unsigned short* __restrict__ t1, const unsigned short* __restrict__ resid,
    const float* __restrict__ w, const float* __restrict__ b,
    unsigned short* __restrict__ out)
{
    const int lane = threadIdx.x & 63;
    const int wv = threadIdx.x >> 6;
    const int row = blockIdx.x * 4 + wv;
    const size_t off = (size_t)row * 256 + lane * 4;

    uint2 a2 = *(const uint2*)(t1 + off);
    uint2 r2 = *(const uint2*)(resid + off);
    float t[4];
    t[0] = bf2f((unsigned short)(a2.x & 0xffff)) + bf2f((unsigned short)(r2.x & 0xffff));
    t[1] = bf2f((unsigned short)(a2.x >> 16))   + bf2f((unsigned short)(r2.x >> 16));
    t[2] = bf2f((unsigned short)(a2.y & 0xffff)) + bf2f((unsigned short)(r2.y & 0xffff));
    t[3] = bf2f((unsigned short)(a2.y >> 16))   + bf2f((unsigned short)(r2.y >> 16));

    float s = t[0] + t[1] + t[2] + t[3];
    float sq = t[0] * t[0] + t[1] * t[1] + t[2] * t[2] + t[3] * t[3];
#pragma unroll
    for (int d = 1; d < 64; d <<= 1) {
        s += __shfl_xor(s, d);
        sq += __shfl_xor(sq, d);
    }
    float mean = s / 256.0f;
    float var = fmaxf(sq / 256.0f - mean * mean, 0.0f);
    float inv = 1.0f / sqrtf(var + LN_EPS);
    float4 wc = *(const float4*)(w + lane * 4);
    float4 bc = *(const float4*)(b + lane * 4);
    float o0 = (t[0] - mean) * inv * wc.x + bc.x;
    float o1 = (t[1] - mean) * inv * wc.y + bc.y;
    float o2 = (t[2] - mean) * inv * wc.z + bc.z;
    float o3 = (t[3] - mean) * inv * wc.w + bc.w;
    uint2 ob;
    ob.x = (unsigned int)f2bf(o0) | ((unsigned int)f2bf(o1) << 16);
    ob.y = (unsigned int)f2bf(o2) | ((unsigned int)f2bf(o3) << 16);
    *(uint2*)(out + off) = ob;
}

// ---------------------------------------------------------------------------
// Frame score from bf16 h: fs = h . fs2_W + fs2_b, masked.  One wave/row.
// ---------------------------------------------------------------------------
__global__ __launch_bounds__(256) void frame_score_kernel(
    const unsigned short* __restrict__ hbuf, const float* __restrict__ w2,
    const float* __restrict__ b2, const int* __restrict__ lens,
    float* __restrict__ frame_out)
{
    const int lane = threadIdx.x & 63;
    const int wv = threadIdx.x >> 6;
    const int rowm = blockIdx.x * 4 + wv;
    uint2 h2 = *(const uint2*)(hbuf + (size_t)rowm * 256 + lane * 4);
    float4 w4 = *(const float4*)(w2 + lane * 4);
    float s = bf2f((unsigned short)(h2.x & 0xffff)) * w4.x +
              bf2f((unsigned short)(h2.x >> 16)) * w4.y +
              bf2f((unsigned short)(h2.y & 0xffff)) * w4.z +
              bf2f((unsigned short)(h2.y >> 16)) * w4.w;
#pragma unroll
    for (int d = 1; d < 64; d <<= 1) s += __shfl_xor(s, d);
    if (lane == 0) {
        int b = rowm >> 10, t = rowm & 1023;
        float fs = s + b2[0];
        frame_out[rowm] = (t < lens[b]) ? fs : 0.0f;
    }
}

// ---------------------------------------------------------------------------
__global__ __launch_bounds__(64) void phoneme_kernel(
    const float* __restrict__ frame, const int* __restrict__ plen,
    float* __restrict__ pscore, float* __restrict__ utt,
    float* __restrict__ flu, float* __restrict__ pros)
{
    __shared__ float cs[T_ + 1];
    __shared__ float ps[P_];
    __shared__ int pmk[P_];

    const int b = blockIdx.x;
    const int lane = threadIdx.x;

    float loc[16];
    float run = 0.0f;
#pragma unroll
    for (int i = 0; i < 16; ++i) {
        run += frame[(size_t)b * T_ + lane * 16 + i];
        loc[i] = run;
    }
    float lanesum = run;
    float incl = lanesum;
#pragma unroll
    for (int d = 1; d < 64; d <<= 1) {
        float y = __shfl_up(incl, d);
        if (lane >= d) incl += y;
    }
    float excl = incl - lanesum;
#pragma unroll
    for (int i = 0; i < 16; ++i) cs[lane * 16 + i + 1] = loc[i] + excl;
    if (lane == 0) cs[0] = 0.0f;
    __syncthreads();

    if (lane == 0) {
        int cum = 0, valid = 1;
        float psum = 0.0f;
        int pcnt = 0;
        for (int p = 0; p < P_; ++p) {
            int lp = plen[b * P_ + p];
            if (lp <= 0) valid = 0;
            int eff = valid ? lp : 0;
            int start = cum; if (start > T_) start = T_; if (start < 0) start = 0;
            cum += eff;
            int end = cum; if (end > T_) end = T_; if (end < 0) end = 0;
            int cnt = end - start;
            float score = (cnt > 0) ? (cs[end] - cs[start]) / (float)cnt : 0.0f;
            ps[p] = score;
            pmk[p] = (lp > 0) ? 1 : 0;
            if (lp > 0) { psum += score; pcnt += 1; }
            pscore[b * P_ + p] = score;
        }
        int pc = pcnt > 0 ? pcnt : 1;
        float u = psum / (float)pc;
        float vsum = 0.0f;
        for (int p = 0; p < P_; ++p) {
            float d = ps[p] - u;
            if (pmk[p]) vsum += d * d;
        }
        float pstd = sqrtf(vsum / (float)pc);
        float f = 100.0f - fminf(pstd * 10.0f, 100.0f);
        f = fmaxf(f, 0.0f);
        utt[b] = u;
        flu[b] = f;
        pros[b] = 0.5f * (u + f);
    }
}

// ---------------------------------------------------------------------------
extern "C" void kernel_launch(void* const* d_in, const int* in_sizes, int n_in,
                              void* d_out, int out_size, void* d_ws, size_t ws_size,
                              hipStream_t stream)
{
    const float* features = (const float*)d_in[0];
    const int* feat_len = (const int*)d_in[1];
    const int* plen = (const int*)d_in[2];
    const float* ssl_W = (const float*)d_in[3];
    const float* ssl_b = (const float*)d_in[4];
    const float* ln0_w = (const float*)d_in[5];
    const float* ln0_b = (const float*)d_in[6];
    const float* conv_W = (const float*)d_in[7];
    const float* conv_b = (const float*)d_in[8];
    const float* qkv_W = (const float*)d_in[9];
    const float* qkv_b = (const float*)d_in[10];
    const float* out_W = (const float*)d_in[11];
    const float* out_b = (const float*)d_in[12];
    const float* ln1_w = (const float*)d_in[13];
    const float* ln1_b = (const float*)d_in[14];
    const float* ff1_W = (const float*)d_in[15];
    const float* ff1_b = (const float*)d_in[16];
    const float* ff2_W = (const float*)d_in[17];
    const float* ff2_b = (const float*)d_in[18];
    const float* ln2_w = (const float*)d_in[19];
    const float* ln2_b = (const float*)d_in[20];
    const float* fs1_W = (const float*)d_in[21];
    const float* fs1_b = (const float*)d_in[22];
    const float* fs2_W = (const float*)d_in[23];
    const float* fs2_b = (const float*)d_in[24];

    // --- workspace layout (all activations bf16) ---
    char* base = (char*)d_ws;
    unsigned short* FFb = (unsigned short*)base;               // M*2048 bf16
    unsigned short* featb = FFb;                               // alias (M*1024)
    unsigned short* QKVb = (unsigned short*)(base + (size_t)M_ * 2048 * 2);  // M*768
    unsigned short* x512b = QKVb;                              // alias (M*512)
    unsigned short* Xb = (unsigned short*)((char*)QKVb + (size_t)M_ * 768 * 2);
    unsigned short* Ob = Xb + (size_t)M_ * 256;
    unsigned short* T1b = Ob + (size_t)M_ * 256;
    unsigned short* sslWb = T1b + (size_t)M_ * 256;
    unsigned short* convWb = sslWb + 512 * 1024;
    unsigned short* qkvWb = convWb + 3 * 256 * 512;
    unsigned short* outWb = qkvWb + (size_t)L_ * 768 * 256;
    unsigned short* ff1Wb = outWb + (size_t)L_ * 256 * 256;
    unsigned short* ff2Wb = ff1Wb + (size_t)L_ * 2048 * 256;
    unsigned short* fs1Wb = ff2Wb + (size_t)L_ * 256 * 2048;

    float* frame = (float*)d_out;
    float* pscore = frame + M_;
    float* uttp = pscore + B_ * P_;
    float* flup = uttp + B_;
    float* prosp = flup + B_;

    // 0) convert weights + features to bf16
    cvt_f2b<<<8192, 256, 0, stream>>>(features, featb);
    cvt_f2b<<<256, 256, 0, stream>>>(ssl_W, sslWb);
    cvt_convw<<<1536, 256, 0, stream>>>(conv_W, convWb);
    cvt_f2b<<<384, 256, 0, stream>>>(qkv_W, qkvWb);
    cvt_f2b<<<128, 256, 0, stream>>>(out_W, outWb);
    cvt_f2b<<<1024, 256, 0, stream>>>(ff1_W, ff1Wb);
    cvt_f2b<<<1024, 256, 0, stream>>>(ff2_W, ff2Wb);
    cvt_f2b<<<32, 256, 0, stream>>>(fs1_W, fs1Wb);

    // 1) SSL linear + ReLU -> x512b (bf16), then LN0 in place
    gemm_ll<1, 1><<<dim3(SSL_ / 128, M_ / 128), 256, 0, stream>>>(
        featb, sslWb, ssl_b, x512b, M_, SSL_, FIN_);
    ln0_bf16<<<M_ / 4, 256, 0, stream>>>(x512b, ln0_w, ln0_b, x512b);

    // 2) Conv1d + ReLU -> Xb (bf16)
    conv_mfma<<<dim3(2, M_ / 128), 256, 0, stream>>>(x512b, convWb, conv_b, Xb);

    // 3) Transformer layers (residual stream bf16 in Xb)
    for (int l = 0; l < L_; ++l) {
        gemm_ll<0, 1><<<dim3(768 / 128, M_ / 128), 256, 0, stream>>>(
            Xb, qkvWb + (size_t)l * 768 * 256, qkv_b + l * 768, QKVb, M_, 768, 256);
        attn_mfma<<<dim3(8, H_, B_), 512, 0, stream>>>(QKVb, feat_len, Ob);
        gemm_ll<0, 1><<<dim3(256 / 128, M_ / 128), 256, 0, stream>>>(
            Ob, outWb + (size_t)l * 256 * 256, out_b + l * 256, T1b, M_, 256, 256);
        ln_res_bf16<<<M_ / 4, 256, 0, stream>>>(
            T1b, Xb, ln1_w + l * 256, ln1_b + l * 256, Xb);
        gemm_ll<1, 1><<<dim3(FF_ / 128, M_ / 128), 256, 0, stream>>>(
            Xb, ff1Wb + (size_t)l * FF_ * 256, ff1_b + l * FF_, FFb, M_, FF_, 256);
        gemm_ll<0, 1><<<dim3(256 / 128, M_ / 128), 256, 0, stream>>>(
            FFb, ff2Wb + (size_t)l * 256 * FF_, ff2_b + l * 256, T1b, M_, 256, FF_);
        ln_res_bf16<<<M_ / 4, 256, 0, stream>>>(
            T1b, Xb, ln2_w + l * 256, ln2_b + l * 256, Xb);
    }

    // 4) Frame scorer (h in bf16)
    gemm_ll<1, 1><<<dim3(256 / 128, M_ / 128), 256, 0, stream>>>(
        Xb, fs1Wb, fs1_b, T1b, M_, 256, 256);
    frame_score_kernel<<<M_ / 4, 256, 0, stream>>>(T1b, fs2_W, fs2_b, feat_len, frame);

    // 5) Phoneme/utterance epilogue
    phoneme_kernel<<<B_, 64, 0, stream>>>(frame, plen, pscore, uttp, flup, prosp);
}

// Round 12
// 900.843 us; speedup vs baseline: 9.6928x; 1.0364x over previous
//
#include <hip/hip_runtime.h>
#include <math.h>

#define B_   16
#define T_   1024
#define FIN_ 1024
#define SSL_ 512
#define D_   256
#define H_   4
#define HD_  64
#define L_   4
#define P_   128
#define FF_  2048
#define M_   (B_ * T_)
#define LN_EPS 1e-5f

typedef __attribute__((ext_vector_type(8))) short bf16x8;
typedef __attribute__((ext_vector_type(4))) float f32x4;

__device__ inline unsigned short f2bf(float f) {
    unsigned int u = __float_as_uint(f);
    u += 0x7fffu + ((u >> 16) & 1u);   // round-to-nearest-even
    return (unsigned short)(u >> 16);
}
__device__ inline float bf2f(unsigned short h) {
    return __uint_as_float(((unsigned int)h) << 16);
}
__device__ inline bf16x8 pack8(float4 a, float4 b) {
    bf16x8 t;
    t[0] = (short)f2bf(a.x); t[1] = (short)f2bf(a.y);
    t[2] = (short)f2bf(a.z); t[3] = (short)f2bf(a.w);
    t[4] = (short)f2bf(b.x); t[5] = (short)f2bf(b.y);
    t[6] = (short)f2bf(b.z); t[7] = (short)f2bf(b.w);
    return t;
}
__device__ inline void glds16(const unsigned short* g, unsigned short* l) {
    __builtin_amdgcn_global_load_lds(
        (const __attribute__((address_space(1))) void*)g,
        (__attribute__((address_space(3))) void*)l, 16, 0, 0);
}

// ---------------------------------------------------------------------------
// fp32 -> bf16 converters (weights + features, run once per launch)
// ---------------------------------------------------------------------------
__global__ __launch_bounds__(256) void cvt_f2b(
    const float* __restrict__ s, unsigned short* __restrict__ d)
{
    size_t i = ((size_t)blockIdx.x * 256 + threadIdx.x) * 8;
    float4 a = *(const float4*)(s + i);
    float4 b = *(const float4*)(s + i + 4);
    *(bf16x8*)(d + i) = pack8(a, b);
}

// conv_W (256,512,3) -> bf16 [kk][n][c]
__global__ __launch_bounds__(256) void cvt_convw(
    const float* __restrict__ s, unsigned short* __restrict__ d)
{
    int i = blockIdx.x * 256 + threadIdx.x;        // 0..393215
    int kk = i >> 17, rem = i & 131071;
    int n = rem >> 9, c = rem & 511;
    d[i] = f2bf(s[(size_t)n * 1536 + c * 3 + kk]);
}

// ---------------------------------------------------------------------------
// bf16 MFMA GEMM (NT), A/B already bf16, staged via global_load_lds dwordx4.
// Unchanged from round 9.
// ---------------------------------------------------------------------------
template <int RELU, int OBF>
__global__ __launch_bounds__(256) void gemm_ll(
    const unsigned short* __restrict__ Ab, const unsigned short* __restrict__ Wb,
    const float* __restrict__ bias, void* __restrict__ Cout,
    int Md, int Nd, int Kd)
{
    __shared__ __align__(16) unsigned short As[128 * 32];
    __shared__ __align__(16) unsigned short Bs[128 * 32];
    char* AsB = (char*)As;
    char* BsB = (char*)Bs;

    const int tid = threadIdx.x;
    const int m0 = blockIdx.y * 128, n0 = blockIdx.x * 128;
    const int w = tid >> 6, l = tid & 63;
    const int lr = l & 15, lg = l >> 4;
    const int wr = w >> 1, wc = w & 1;

    f32x4 acc[4][4];
#pragma unroll
    for (int mi = 0; mi < 4; ++mi)
#pragma unroll
        for (int ni = 0; ni < 4; ++ni) acc[mi][ni] = (f32x4){0.f, 0.f, 0.f, 0.f};

    int aoff[4], boff[4];
#pragma unroll
    for (int mi = 0; mi < 4; ++mi) {
        int row = wr * 64 + mi * 16 + lr;
        aoff[mi] = row * 64 + ((lg * 16) ^ (((row >> 1) & 3) << 4));
    }
#pragma unroll
    for (int ni = 0; ni < 4; ++ni) {
        int row = wc * 64 + ni * 16 + lr;
        boff[ni] = row * 64 + ((lg * 16) ^ (((row >> 1) & 3) << 4));
    }
    int srow[2], scp[2];
#pragma unroll
    for (int j = 0; j < 2; ++j) {
        int row = (w * 2 + j) * 16 + (l >> 2);
        srow[j] = row;
        scp[j] = (l & 3) ^ ((row >> 1) & 3);
    }

    for (int k0 = 0; k0 < Kd; k0 += 32) {
        __syncthreads();
#pragma unroll
        for (int j = 0; j < 2; ++j) {
            glds16(Ab + (size_t)(m0 + srow[j]) * Kd + k0 + scp[j] * 8,
                   As + (w * 2 + j) * 512);
            glds16(Wb + (size_t)(n0 + srow[j]) * Kd + k0 + scp[j] * 8,
                   Bs + (w * 2 + j) * 512);
        }
        __syncthreads();
        bf16x8 a[4], bb[4];
#pragma unroll
        for (int mi = 0; mi < 4; ++mi) a[mi] = *(bf16x8*)(AsB + aoff[mi]);
#pragma unroll
        for (int ni = 0; ni < 4; ++ni) bb[ni] = *(bf16x8*)(BsB + boff[ni]);
#pragma unroll
        for (int mi = 0; mi < 4; ++mi)
#pragma unroll
            for (int ni = 0; ni < 4; ++ni)
                acc[mi][ni] = __builtin_amdgcn_mfma_f32_16x16x32_bf16(
                    a[mi], bb[ni], acc[mi][ni], 0, 0, 0);
    }

#pragma unroll
    for (int ni = 0; ni < 4; ++ni) {
        int col = n0 + wc * 64 + ni * 16 + lr;
        float bj = bias[col];
#pragma unroll
        for (int mi = 0; mi < 4; ++mi) {
#pragma unroll
            for (int r = 0; r < 4; ++r) {
                int rowg = m0 + wr * 64 + mi * 16 + lg * 4 + r;
                float v = acc[mi][ni][r] + bj;
                if (RELU) v = fmaxf(v, 0.0f);
                if (OBF) {
                    ((unsigned short*)Cout)[(size_t)rowg * Nd + col] = f2bf(v);
                } else {
                    ((float*)Cout)[(size_t)rowg * Nd + col] = v;
                }
            }
        }
    }
}

// ---------------------------------------------------------------------------
// Conv1d k=3 pad=1 as bf16 MFMA.  Unchanged from round 9.
// ---------------------------------------------------------------------------
__global__ __launch_bounds__(256) void conv_mfma(
    const unsigned short* __restrict__ xb, const unsigned short* __restrict__ wb,
    const float* __restrict__ cb, unsigned short* __restrict__ Xb)
{
    __shared__ __align__(16) unsigned short As[130 * 32];
    __shared__ __align__(16) unsigned short Bs[3 * 128 * 32];
    char* AsB = (char*)As;
    char* BsB = (char*)Bs;

    const int tid = threadIdx.x;
    const int n0 = blockIdx.x * 128, m0 = blockIdx.y * 128;
    const int t0 = m0 & 1023;
    const int w = tid >> 6, l = tid & 63;
    const int lr = l & 15, lg = l >> 4;
    const int wr = w >> 1, wc = w & 1;

    f32x4 acc[4][4];
#pragma unroll
    for (int mi = 0; mi < 4; ++mi)
#pragma unroll
        for (int ni = 0; ni < 4; ++ni) acc[mi][ni] = (f32x4){0.f, 0.f, 0.f, 0.f};

    int aoff[4][3], boff[4][3];
#pragma unroll
    for (int mi = 0; mi < 4; ++mi)
#pragma unroll
        for (int kk = 0; kk < 3; ++kk) {
            int row = wr * 64 + mi * 16 + lr + kk;   // local A row (0..129)
            aoff[mi][kk] = row * 64 + ((lg * 16) ^ (((row >> 1) & 3) << 4));
        }
#pragma unroll
    for (int ni = 0; ni < 4; ++ni) {
        int nl = wc * 64 + ni * 16 + lr;
#pragma unroll
        for (int kk = 0; kk < 3; ++kk)
            boff[ni][kk] = kk * 8192 + nl * 64 + ((lg * 16) ^ (((nl >> 1) & 3) << 4));
    }

    for (int c0 = 0; c0 < 512; c0 += 32) {
        __syncthreads();
#pragma unroll
        for (int it = 0; it < 3; ++it) {
            int id = tid + it * 256;
            if (id < 520) {
                int r = id >> 2, ch = id & 3;
                int t = t0 + r - 1;
                bf16x8 v = (bf16x8){0, 0, 0, 0, 0, 0, 0, 0};
                if ((unsigned)t < 1024u)
                    v = *(const bf16x8*)(xb + (size_t)(m0 + r - 1) * 512 + c0 + ch * 8);
                *(bf16x8*)(AsB + r * 64 + ((ch * 16) ^ (((r >> 1) & 3) << 4))) = v;
            }
        }
#pragma unroll
        for (int it = 0; it < 6; ++it) {
            int id = tid + it * 256;
            int kk = id >> 9, rem = id & 511;
            int nl = rem >> 2, ch = rem & 3;
            bf16x8 v = *(const bf16x8*)(wb + (size_t)kk * 131072 +
                                        (size_t)(n0 + nl) * 512 + c0 + ch * 8);
            *(bf16x8*)(BsB + kk * 8192 + nl * 64 +
                       ((ch * 16) ^ (((nl >> 1) & 3) << 4))) = v;
        }
        __syncthreads();
#pragma unroll
        for (int kk = 0; kk < 3; ++kk) {
            bf16x8 bb[4];
#pragma unroll
            for (int ni = 0; ni < 4; ++ni) bb[ni] = *(bf16x8*)(BsB + boff[ni][kk]);
#pragma unroll
            for (int mi = 0; mi < 4; ++mi) {
                bf16x8 a = *(bf16x8*)(AsB + aoff[mi][kk]);
#pragma unroll
                for (int ni = 0; ni < 4; ++ni)
                    acc[mi][ni] = __builtin_amdgcn_mfma_f32_16x16x32_bf16(
                        a, bb[ni], acc[mi][ni], 0, 0, 0);
            }
        }
    }

#pragma unroll
    for (int ni = 0; ni < 4; ++ni) {
        int col = n0 + wc * 64 + ni * 16 + lr;
        float bj = cb[col];
#pragma unroll
        for (int mi = 0; mi < 4; ++mi) {
#pragma unroll
            for (int r = 0; r < 4; ++r) {
                int m = m0 + wr * 64 + mi * 16 + lg * 4 + r;
                float v = fmaxf(acc[mi][ni][r] + bj, 0.0f);
                Xb[(size_t)m * 256 + col] = f2bf(v);
            }
        }
    }
}

// ---------------------------------------------------------------------------
// bf16 MFMA flash attention, 128 q-rows/block (8 waves, 512 thr).
// r10: T14 async-STAGE split (issue loads for tile t+1 before computing
// tile t; vmcnt-wait + ds_write after the post-compute barrier), paired
// V-transpose writes (4x b32 instead of 8x b16), defer-max (THR=8),
// wave-uniform full-tile mask skip.
// ---------------------------------------------------------------------------
__global__ __launch_bounds__(512) void attn_mfma(
    const unsigned short* __restrict__ qkvb, const int* __restrict__ lens,
    unsigned short* __restrict__ Ob)
{
    __shared__ __align__(16) unsigned short Kt[64 * 64];     // [k][hd]
    __shared__ __align__(16) unsigned short Vt[64 * 64];     // [d][k]
    __shared__ __align__(16) unsigned short Pt[8][16 * 64];  // per-wave [q][k]

    const int qt = blockIdx.x, h = blockIdx.y, b = blockIdx.z;
    const int tid = threadIdx.x;
    const int w = tid >> 6, l = tid & 63;
    const int lr = l & 15, lg = l >> 4;
    const int len = lens[b];
    const int nt = (len + 63) >> 6;          // tiles with any valid k (<= 16)
    const size_t base = (size_t)b * (T_ * 768);
    const int q0 = qt * 128 + w * 16;

    char* KtB = (char*)Kt;
    char* VtB = (char*)Vt;
    char* PtB = (char*)(Pt[w]);

    bf16x8 qf[2];
#pragma unroll
    for (int half = 0; half < 2; ++half)
        qf[half] = *(const bf16x8*)(qkvb + base + (size_t)(q0 + lr) * 768 +
                                    h * 64 + lg * 8 + half * 32);

    float mrun = -3e38f, lrun = 0.0f;
    f32x4 acc_o[4];
#pragma unroll
    for (int td = 0; td < 4; ++td) acc_o[td] = (f32x4){0.f, 0.f, 0.f, 0.f};

    // --- staging geometry (512 threads) ---
    // K: 64 rows x 8 chunks = 512 tasks, 1/thread
    const int skr = tid >> 3, skc = tid & 7;
    const int kOff = skr * 128 + ((skc << 4) ^ ((skr & 7) << 4));
    const unsigned short* kSrc = qkvb + base + h * 64 + 256 +
                                 (size_t)skr * 768 + skc * 8;
    // V: 32 k-pairs x 16 d-quads = 512 tasks, 1/thread (paired b32 writes)
    const int vkp = tid >> 4, vdq = tid & 15;
    const int d0 = vdq * 4;
    const int vO0 = (d0 + 0) * 128 + ((4 * vkp) ^ (((d0 + 0) & 7) << 4));
    const int vO1 = (d0 + 1) * 128 + ((4 * vkp) ^ (((d0 + 1) & 7) << 4));
    const int vO2 = (d0 + 2) * 128 + ((4 * vkp) ^ (((d0 + 2) & 7) << 4));
    const int vO3 = (d0 + 3) * 128 + ((4 * vkp) ^ (((d0 + 3) & 7) << 4));
    const unsigned short* vSrcA = qkvb + base + h * 64 + 512 +
                                  (size_t)(2 * vkp) * 768 + d0;
    const unsigned short* vSrcB = vSrcA + 768;

    // --- prologue: load tile 0 into registers ---
    bf16x8 kreg = *(const bf16x8*)kSrc;
    uint2 va = *(const uint2*)vSrcA;
    uint2 vb = *(const uint2*)vSrcB;

    for (int tk = 0; tk < nt; ++tk) {
        const int kv0 = tk * 64;
        __syncthreads();                       // prev-tile LDS reads done
        // write staged regs -> LDS (vmcnt wait was hidden under prev compute)
        *(bf16x8*)(KtB + kOff) = kreg;
        {
            unsigned int w0 = (va.x & 0xffffu) | (vb.x << 16);
            unsigned int w1 = (va.x >> 16) | (vb.x & 0xffff0000u);
            unsigned int w2 = (va.y & 0xffffu) | (vb.y << 16);
            unsigned int w3 = (va.y >> 16) | (vb.y & 0xffff0000u);
            *(unsigned int*)(VtB + vO0) = w0;
            *(unsigned int*)(VtB + vO1) = w1;
            *(unsigned int*)(VtB + vO2) = w2;
            *(unsigned int*)(VtB + vO3) = w3;
        }
        __syncthreads();
        // issue next tile's loads BEFORE compute (latency hides under it)
        if (tk + 1 < nt) {
            size_t nb = (size_t)(tk + 1) * 64 * 768;
            kreg = *(const bf16x8*)(kSrc + nb);
            va = *(const uint2*)(vSrcA + nb);
            vb = *(const uint2*)(vSrcB + nb);
        }

        // --- QK^T (swapped: S^T = K.Q^T) ---
        f32x4 accs[4];
        __builtin_amdgcn_s_setprio(1);
#pragma unroll
        for (int kt = 0; kt < 4; ++kt) {
            int row = kt * 16 + lr;
            int rb = row * 128, sw = (row & 7) << 4;
            bf16x8 k0 = *(bf16x8*)(KtB + rb + ((lg * 16) ^ sw));
            bf16x8 k1 = *(bf16x8*)(KtB + rb + ((lg * 16 + 64) ^ sw));
            f32x4 z = (f32x4){0.f, 0.f, 0.f, 0.f};
            f32x4 t = __builtin_amdgcn_mfma_f32_16x16x32_bf16(k0, qf[0], z, 0, 0, 0);
            accs[kt] = __builtin_amdgcn_mfma_f32_16x16x32_bf16(k1, qf[1], t, 0, 0, 0);
        }
        __builtin_amdgcn_s_setprio(0);

        // --- mask + online softmax (defer-max) ---
        float p[16];
        float pmax = -3e38f;
        if (kv0 + 64 <= len) {                 // wave-uniform: fully valid tile
#pragma unroll
            for (int i = 0; i < 16; ++i) {
                float v = accs[i >> 2][i & 3] * 0.125f;
                p[i] = v;
                pmax = fmaxf(pmax, v);
            }
        } else {
#pragma unroll
            for (int kt = 0; kt < 4; ++kt)
#pragma unroll
                for (int r = 0; r < 4; ++r) {
                    int kidx = kv0 + kt * 16 + lg * 4 + r;
                    float v = (kidx < len) ? accs[kt][r] * 0.125f : -1e30f;
                    p[kt * 4 + r] = v;
                    pmax = fmaxf(pmax, v);
                }
        }
        pmax = fmaxf(pmax, __shfl_xor(pmax, 16));
        pmax = fmaxf(pmax, __shfl_xor(pmax, 32));

        float alpha = 1.0f;
        if (!__all((int)(pmax <= mrun + 8.0f))) {   // defer-max (THR=8)
            float mnew = fmaxf(mrun, pmax);
            alpha = __expf(mrun - mnew);
            mrun = mnew;
#pragma unroll
            for (int td = 0; td < 4; ++td) acc_o[td] *= alpha;
        }
        float psum = 0.0f;
#pragma unroll
        for (int i = 0; i < 16; ++i) {
            float e = __expf(p[i] - mrun);
            p[i] = e;
            psum += e;
        }
        psum += __shfl_xor(psum, 16);
        psum += __shfl_xor(psum, 32);
        lrun = lrun * alpha + psum;

        // --- P^T -> LDS (bf16), then PV: O^T = V^T . P ---
        const int swq = (lr & 7) << 4;
#pragma unroll
        for (int kt = 0; kt < 4; ++kt) {
            unsigned int p01 = (unsigned int)f2bf(p[kt * 4 + 0]) |
                               ((unsigned int)f2bf(p[kt * 4 + 1]) << 16);
            unsigned int p23 = (unsigned int)f2bf(p[kt * 4 + 2]) |
                               ((unsigned int)f2bf(p[kt * 4 + 3]) << 16);
            uint2 pw; pw.x = p01; pw.y = p23;
            *(uint2*)(PtB + lr * 128 + ((kt * 32 + lg * 8) ^ swq)) = pw;
        }
        bf16x8 pf0 = *(bf16x8*)(PtB + lr * 128 + ((lg * 16) ^ swq));
        bf16x8 pf1 = *(bf16x8*)(PtB + lr * 128 + ((lg * 16 + 64) ^ swq));
        __builtin_amdgcn_s_setprio(1);
#pragma unroll
        for (int td = 0; td < 4; ++td) {
            int d = td * 16 + lr;
            int db = d * 128, swd = (d & 7) << 4;
            bf16x8 v0 = *(bf16x8*)(VtB + db + ((lg * 16) ^ swd));
            bf16x8 v1 = *(bf16x8*)(VtB + db + ((lg * 16 + 64) ^ swd));
            acc_o[td] = __builtin_amdgcn_mfma_f32_16x16x32_bf16(v0, pf0, acc_o[td], 0, 0, 0);
            acc_o[td] = __builtin_amdgcn_mfma_f32_16x16x32_bf16(v1, pf1, acc_o[td], 0, 0, 0);
        }
        __builtin_amdgcn_s_setprio(0);
    }

    float inv = 1.0f / lrun;
    const int tglob = q0 + lr;
#pragma unroll
    for (int td = 0; td < 4; ++td)
#pragma unroll
        for (int r = 0; r < 4; ++r) {
            int d = td * 16 + lg * 4 + r;
            Ob[((size_t)b * T_ + tglob) * 256 + h * 64 + d] = f2bf(acc_o[td][r] * inv);
        }
}

// ---------------------------------------------------------------------------
// LN0: bf16 in (M,512), bf16 out, no residual.  One wave per row.
// ---------------------------------------------------------------------------
__global__ __launch_bounds__(256) void ln0_bf16(
    const unsigned short* __restrict__ xin, const float* __restrict__ w,
    const float* __restrict__ b, unsigned short* __restrict__ out)
{
    const int lane = threadIdx.x & 63;
    const int wv = threadIdx.x >> 6;
    const int row = blockIdx.x * 4 + wv;

    bf16x8 v8 = *(const bf16x8*)(xin + (size_t)row * 512 + lane * 8);
    float f[8];
    float s = 0.0f, sq = 0.0f;
#pragma unroll
    for (int j = 0; j < 8; ++j) {
        f[j] = bf2f((unsigned short)v8[j]);
        s += f[j];
        sq += f[j] * f[j];
    }
#pragma unroll
    for (int d = 1; d < 64; d <<= 1) {
        s += __shfl_xor(s, d);
        sq += __shfl_xor(sq, d);
    }
    float mean = s / 512.0f;
    float var = fmaxf(sq / 512.0f - mean * mean, 0.0f);
    float inv = 1.0f / sqrtf(var + LN_EPS);
    float4 w0 = *(const float4*)(w + lane * 8);
    float4 w1 = *(const float4*)(w + lane * 8 + 4);
    float4 b0 = *(const float4*)(b + lane * 8);
    float4 b1 = *(const float4*)(b + lane * 8 + 4);
    float wv8[8] = {w0.x, w0.y, w0.z, w0.w, w1.x, w1.y, w1.z, w1.w};
    float bv8[8] = {b0.x, b0.y, b0.z, b0.w, b1.x, b1.y, b1.z, b1.w};
    bf16x8 o;
#pragma unroll
    for (int j = 0; j < 8; ++j)
        o[j] = (short)f2bf((f[j] - mean) * inv * wv8[j] + bv8[j]);
    *(bf16x8*)(out + (size_t)row * 512 + lane * 8) = o;
}

// ---------------------------------------------------------------------------
// LN (W=256), all-bf16: out = LN(t1 + resid) -> bf16.  One wave per row.
// ---------------------------------------------------------------------------
__global__ __launch_bounds__(256) void ln_res_bf16(
    const unsigned short* __restrict__ t1, const unsigned short* __restrict__ resid,
    const float* __restrict__ w, const float* __restrict__ b,
    unsigned short* __restrict__ out)
{
    const int lane = threadIdx.x & 63;
    const int wv = threadIdx.x >> 6;
    const int row = blockIdx.x * 4 + wv;
    const size_t off = (size_t)row * 256 + lane * 4;

    uint2 a2 = *(const uint2*)(t1 + off);
    uint2 r2 = *(const uint2*)(resid + off);
    float t[4];
    t[0] = bf2f((unsigned short)(a2.x & 0xffff)) + bf2f((unsigned short)(r2.x & 0xffff));
    t[1] = bf2f((unsigned short)(a2.x >> 16))   + bf2f((unsigned short)(r2.x >> 16));
    t[2] = bf2f((unsigned short)(a2.y & 0xffff)) + bf2f((unsigned short)(r2.y & 0xffff));
    t[3] = bf2f((unsigned short)(a2.y >> 16))   + bf2f((unsigned short)(r2.y >> 16));

    float s = t[0] + t[1] + t[2] + t[3];
    float sq = t[0] * t[0] + t[1] * t[1] + t[2] * t[2] + t[3] * t[3];
#pragma unroll
    for (int d = 1; d < 64; d <<= 1) {
        s += __shfl_xor(s, d);
        sq += __shfl_xor(sq, d);
    }
    float mean = s / 256.0f;
    float var = fmaxf(sq / 256.0f - mean * mean, 0.0f);
    float inv = 1.0f / sqrtf(var + LN_EPS);
    float4 wc = *(const float4*)(w + lane * 4);
    float4 bc = *(const float4*)(b + lane * 4);
    float o0 = (t[0] - mean) * inv * wc.x + bc.x;
    float o1 = (t[1] - mean) * inv * wc.y + bc.y;
    float o2 = (t[2] - mean) * inv * wc.z + bc.z;
    float o3 = (t[3] - mean) * inv * wc.w + bc.w;
    uint2 ob;
    ob.x = (unsigned int)f2bf(o0) | ((unsigned int)f2bf(o1) << 16);
    ob.y = (unsigned int)f2bf(o2) | ((unsigned int)f2bf(o3) << 16);
    *(uint2*)(out + off) = ob;
}

// ---------------------------------------------------------------------------
// Frame score from bf16 h: fs = h . fs2_W + fs2_b, masked.  One wave/row.
// ---------------------------------------------------------------------------
__global__ __launch_bounds__(256) void frame_score_kernel(
    const unsigned short* __restrict__ hbuf, const float* __restrict__ w2,
    const float* __restrict__ b2, const int* __restrict__ lens,
    float* __restrict__ frame_out)
{
    const int lane = threadIdx.x & 63;
    const int wv = threadIdx.x >> 6;
    const int rowm = blockIdx.x * 4 + wv;
    uint2 h2 = *(const uint2*)(hbuf + (size_t)rowm * 256 + lane * 4);
    float4 w4 = *(const float4*)(w2 + lane * 4);
    float s = bf2f((unsigned short)(h2.x & 0xffff)) * w4.x +
              bf2f((unsigned short)(h2.x >> 16)) * w4.y +
              bf2f((unsigned short)(h2.y & 0xffff)) * w4.z +
              bf2f((unsigned short)(h2.y >> 16)) * w4.w;
#pragma unroll
    for (int d = 1; d < 64; d <<= 1) s += __shfl_xor(s, d);
    if (lane == 0) {
        int b = rowm >> 10, t = rowm & 1023;
        float fs = s + b2[0];
        frame_out[rowm] = (t < lens[b]) ? fs : 0.0f;
    }
}

// ---------------------------------------------------------------------------
__global__ __launch_bounds__(64) void phoneme_kernel(
    const float* __restrict__ frame, const int* __restrict__ plen,
    float* __restrict__ pscore, float* __restrict__ utt,
    float* __restrict__ flu, float* __restrict__ pros)
{
    __shared__ float cs[T_ + 1];
    __shared__ float ps[P_];
    __shared__ int pmk[P_];

    const int b = blockIdx.x;
    const int lane = threadIdx.x;

    float loc[16];
    float run = 0.0f;
#pragma unroll
    for (int i = 0; i < 16; ++i) {
        run += frame[(size_t)b * T_ + lane * 16 + i];
        loc[i] = run;
    }
    float lanesum = run;
    float incl = lanesum;
#pragma unroll
    for (int d = 1; d < 64; d <<= 1) {
        float y = __shfl_up(incl, d);
        if (lane >= d) incl += y;
    }
    float excl = incl - lanesum;
#pragma unroll
    for (int i = 0; i < 16; ++i) cs[lane * 16 + i + 1] = loc[i] + excl;
    if (lane == 0) cs[0] = 0.0f;
    __syncthreads();

    if (lane == 0) {
        int cum = 0, valid = 1;
        float psum = 0.0f;
        int pcnt = 0;
        for (int p = 0; p < P_; ++p) {
            int lp = plen[b * P_ + p];
            if (lp <= 0) valid = 0;
            int eff = valid ? lp : 0;
            int start = cum; if (start > T_) start = T_; if (start < 0) start = 0;
            cum += eff;
            int end = cum; if (end > T_) end = T_; if (end < 0) end = 0;
            int cnt = end - start;
            float score = (cnt > 0) ? (cs[end] - cs[start]) / (float)cnt : 0.0f;
            ps[p] = score;
            pmk[p] = (lp > 0) ? 1 : 0;
            if (lp > 0) { psum += score; pcnt += 1; }
            pscore[b * P_ + p] = score;
        }
        int pc = pcnt > 0 ? pcnt : 1;
        float u = psum / (float)pc;
        float vsum = 0.0f;
        for (int p = 0; p < P_; ++p) {
            float d = ps[p] - u;
            if (pmk[p]) vsum += d * d;
        }
        float pstd = sqrtf(vsum / (float)pc);
        float f = 100.0f - fminf(pstd * 10.0f, 100.0f);
        f = fmaxf(f, 0.0f);
        utt[b] = u;
        flu[b] = f;
        pros[b] = 0.5f * (u + f);
    }
}

// ---------------------------------------------------------------------------
extern "C" void kernel_launch(void* const* d_in, const int* in_sizes, int n_in,
                              void* d_out, int out_size, void* d_ws, size_t ws_size,
                              hipStream_t stream)
{
    const float* features = (const float*)d_in[0];
    const int* feat_len = (const int*)d_in[1];
    const int* plen = (const int*)d_in[2];
    const float* ssl_W = (const float*)d_in[3];
    const float* ssl_b = (const float*)d_in[4];
    const float* ln0_w = (const float*)d_in[5];
    const float* ln0_b = (const float*)d_in[6];
    const float* conv_W = (const float*)d_in[7];
    const float* conv_b = (const float*)d_in[8];
    const float* qkv_W = (const float*)d_in[9];
    const float* qkv_b = (const float*)d_in[10];
    const float* out_W = (const float*)d_in[11];
    const float* out_b = (const float*)d_in[12];
    const float* ln1_w = (const float*)d_in[13];
    const float* ln1_b = (const float*)d_in[14];
    const float* ff1_W = (const float*)d_in[15];
    const float* ff1_b = (const float*)d_in[16];
    const float* ff2_W = (const float*)d_in[17];
    const float* ff2_b = (const float*)d_in[18];
    const float* ln2_w = (const float*)d_in[19];
    const float* ln2_b = (const float*)d_in[20];
    const float* fs1_W = (const float*)d_in[21];
    const float* fs1_b = (const float*)d_in[22];
    const float* fs2_W = (const float*)d_in[23];
    const float* fs2_b = (const float*)d_in[24];

    // --- workspace layout (all activations bf16) ---
    char* base = (char*)d_ws;
    unsigned short* FFb = (unsigned short*)base;               // M*2048 bf16
    unsigned short* featb = FFb;                               // alias (M*1024)
    unsigned short* QKVb = (unsigned short*)(base + (size_t)M_ * 2048 * 2);  // M*768
    unsigned short* x512b = QKVb;                              // alias (M*512)
    unsigned short* Xb = (unsigned short*)((char*)QKVb + (size_t)M_ * 768 * 2);
    unsigned short* Ob = Xb + (size_t)M_ * 256;
    unsigned short* T1b = Ob + (size_t)M_ * 256;
    unsigned short* sslWb = T1b + (size_t)M_ * 256;
    unsigned short* convWb = sslWb + 512 * 1024;
    unsigned short* qkvWb = convWb + 3 * 256 * 512;
    unsigned short* outWb = qkvWb + (size_t)L_ * 768 * 256;
    unsigned short* ff1Wb = outWb + (size_t)L_ * 256 * 256;
    unsigned short* ff2Wb = ff1Wb + (size_t)L_ * 2048 * 256;
    unsigned short* fs1Wb = ff2Wb + (size_t)L_ * 256 * 2048;

    float* frame = (float*)d_out;
    float* pscore = frame + M_;
    float* uttp = pscore + B_ * P_;
    float* flup = uttp + B_;
    float* prosp = flup + B_;

    // 0) convert weights + features to bf16
    cvt_f2b<<<8192, 256, 0, stream>>>(features, featb);
    cvt_f2b<<<256, 256, 0, stream>>>(ssl_W, sslWb);
    cvt_convw<<<1536, 256, 0, stream>>>(conv_W, convWb);
    cvt_f2b<<<384, 256, 0, stream>>>(qkv_W, qkvWb);
    cvt_f2b<<<128, 256, 0, stream>>>(out_W, outWb);
    cvt_f2b<<<1024, 256, 0, stream>>>(ff1_W, ff1Wb);
    cvt_f2b<<<1024, 256, 0, stream>>>(ff2_W, ff2Wb);
    cvt_f2b<<<32, 256, 0, stream>>>(fs1_W, fs1Wb);

    // 1) SSL linear + ReLU -> x512b (bf16), then LN0 in place
    gemm_ll<1, 1><<<dim3(SSL_ / 128, M_ / 128), 256, 0, stream>>>(
        featb, sslWb, ssl_b, x512b, M_, SSL_, FIN_);
    ln0_bf16<<<M_ / 4, 256, 0, stream>>>(x512b, ln0_w, ln0_b, x512b);

    // 2) Conv1d + ReLU -> Xb (bf16)
    conv_mfma<<<dim3(2, M_ / 128), 256, 0, stream>>>(x512b, convWb, conv_b, Xb);

    // 3) Transformer layers (residual stream bf16 in Xb)
    for (int l = 0; l < L_; ++l) {
        gemm_ll<0, 1><<<dim3(768 / 128, M_ / 128), 256, 0, stream>>>(
            Xb, qkvWb + (size_t)l * 768 * 256, qkv_b + l * 768, QKVb, M_, 768, 256);
        attn_mfma<<<dim3(8, H_, B_), 512, 0, stream>>>(QKVb, feat_len, Ob);
        gemm_ll<0, 1><<<dim3(256 / 128, M_ / 128), 256, 0, stream>>>(
            Ob, outWb + (size_t)l * 256 * 256, out_b + l * 256, T1b, M_, 256, 256);
        ln_res_bf16<<<M_ / 4, 256, 0, stream>>>(
            T1b, Xb, ln1_w + l * 256, ln1_b + l * 256, Xb);
        gemm_ll<1, 1><<<dim3(FF_ / 128, M_ / 128), 256, 0, stream>>>(
            Xb, ff1Wb + (size_t)l * FF_ * 256, ff1_b + l * FF_, FFb, M_, FF_, 256);
        gemm_ll<0, 1><<<dim3(256 / 128, M_ / 128), 256, 0, stream>>>(
            FFb, ff2Wb + (size_t)l * 256 * FF_, ff2_b + l * 256, T1b, M_, 256, FF_);
        ln_res_bf16<<<M_ / 4, 256, 0, stream>>>(
            T1b, Xb, ln2_w + l * 256, ln2_b + l * 256, Xb);
    }

    // 4) Frame scorer (h in bf16)
    gemm_ll<1, 1><<<dim3(256 / 128, M_ / 128), 256, 0, stream>>>(
        Xb, fs1Wb, fs1_b, T1b, M_, 256, 256);
    frame_score_kernel<<<M_ / 4, 256, 0, stream>>>(T1b, fs2_W, fs2_b, feat_len, frame);

    // 5) Phoneme/utterance epilogue
    phoneme_kernel<<<B_, 64, 0, stream>>>(frame, plen, pscore, uttp, flup, prosp);
}